// Round 5
// baseline (728.361 us; speedup 1.0000x reference)
//
#include <hip/hip_runtime.h>
#include <hip/hip_cooperative_groups.h>
#include <stdint.h>

namespace cg = cooperative_groups;

typedef _Float16 f16;
typedef _Float16 half4 __attribute__((ext_vector_type(4)));
typedef _Float16 f16x8 __attribute__((ext_vector_type(8)));
typedef float f32x4 __attribute__((ext_vector_type(4)));

#define BKT_SH 9
#define BKT_SZ 512
#define EB 4096

// ---------------- LDS union (max ~33.8 KB -> 4 blocks/CU) ----------------

struct __attribute__((aligned(16))) MidS {
    f16 Ah[64 * 72];
    f16 Zh[64 * 40];
    f16 WzB[2 * 2 * 64 * 8];
    f16 WdB[4 * 64 * 8];
    float Wcs[32 * 4];
    float bzs[32], bds[64], bcs[4];
};
struct __attribute__((aligned(16))) G1Smem { f16 WB[4 * 8 * 64 * 8]; };               // 32 KB
struct __attribute__((aligned(16))) G5Smem { f16 WB[16 * 2 * 64 * 8]; float bs[256]; }; // 33 KB
struct BinS { int h[128], segs[128], cur[128], s[256]; };
struct CsrS { int cnt[BKT_SZ], exc[BKT_SZ], cur2[BKT_SZ], p[256]; };
union __attribute__((aligned(16))) SmemU { MidS mid; G1Smem g1; G5Smem g5; BinS bin; CsrS csr; int bh[128]; };

// ---------------- CSR device bodies (256 threads) ----------------

__device__ __forceinline__ void dev_bhist(SmemU& sm, const int* __restrict__ dst, int E, int nbk,
                                          int* __restrict__ gcnt, int bid) {
    int* h = sm.bh;
    int tid = threadIdx.x;
    if (tid < 128) h[tid] = 0;
    __syncthreads();
    int base = bid * EB;
    int end = min(base + EB, E);
    for (int i = base + tid; i < end; i += 256) atomicAdd(&h[dst[i] >> BKT_SH], 1);
    __syncthreads();
    if (tid < nbk && h[tid]) atomicAdd(&gcnt[tid], h[tid]);
}

__device__ __forceinline__ void dev_binA(SmemU& sm, const int* __restrict__ src,
                                         const int* __restrict__ dst, int E,
                                         const int* __restrict__ gcnt, int* __restrict__ bcur,
                                         unsigned* __restrict__ ebuf, int bid) {
    int* h = sm.bin.h; int* segs = sm.bin.segs; int* cur = sm.bin.cur; int* s = sm.bin.s;
    int tid = threadIdx.x;
    if (tid < 128) { h[tid] = 0; cur[tid] = 0; }
    __syncthreads();
    int base = bid * EB;
    int end = min(base + EB, E);
    for (int i = base + tid; i < end; i += 256) atomicAdd(&h[dst[i] >> BKT_SH], 1);
    int v = (tid < 128) ? gcnt[tid] : 0;
    s[tid] = v;
    __syncthreads();
    for (int o = 1; o < 256; o <<= 1) {
        int t = (tid >= o) ? s[tid - o] : 0;
        __syncthreads();
        s[tid] += t;
        __syncthreads();
    }
    if (tid < 128) segs[tid] = h[tid] ? (s[tid] - v) + atomicAdd(&bcur[tid], h[tid]) : 0;
    __syncthreads();
    for (int i = base + tid; i < end; i += 256) {
        int d = dst[i];
        int bk = d >> BKT_SH;
        int r = atomicAdd(&cur[bk], 1);
        ebuf[segs[bk] + r] = (unsigned)src[i] | ((unsigned)(d & (BKT_SZ - 1)) << 17);
    }
}

__device__ __forceinline__ void dev_csr(SmemU& sm, const unsigned* __restrict__ ebuf,
                                        const int* __restrict__ gcnt, int n, int E,
                                        int* __restrict__ row_ptr, float* __restrict__ dinv,
                                        int* __restrict__ ssorted, int b) {
    int* cnt = sm.csr.cnt; int* exc = sm.csr.exc; int* cur2 = sm.csr.cur2; int* p = sm.csr.p;
    int tid = threadIdx.x;
    int v = (tid < 128) ? gcnt[tid] : 0;
    p[tid] = v;
    __syncthreads();
    for (int o = 1; o < 256; o <<= 1) {
        int t = (tid >= o) ? p[tid - o] : 0;
        __syncthreads();
        p[tid] += t;
        __syncthreads();
    }
    int scnt = gcnt[b];
    int s0 = p[b] - scnt;
    __syncthreads();
    if (b == 0 && tid == 0) row_ptr[n] = E;

    int d0 = b << BKT_SH;
    int ndl = min(BKT_SZ, n - d0);
    cnt[tid] = 0; cnt[tid + 256] = 0;
    cur2[tid] = 0; cur2[tid + 256] = 0;
    __syncthreads();
    for (int i = tid; i < scnt; i += 256)
        atomicAdd(&cnt[(ebuf[s0 + i] >> 17) & (BKT_SZ - 1)], 1);
    __syncthreads();
    int a = cnt[2 * tid], c2 = cnt[2 * tid + 1];
    p[tid] = a + c2;
    __syncthreads();
    for (int o = 1; o < 256; o <<= 1) {
        int t = (tid >= o) ? p[tid - o] : 0;
        __syncthreads();
        p[tid] += t;
        __syncthreads();
    }
    int pex = p[tid] - (a + c2);
    exc[2 * tid] = pex;
    exc[2 * tid + 1] = pex + a;
    __syncthreads();
    for (int dl = tid; dl < ndl; dl += 256) {
        row_ptr[d0 + dl] = s0 + exc[dl];
        dinv[d0 + dl] = rsqrtf((float)(cnt[dl] + 1));  // +1 self loop
    }
    for (int i = tid; i < scnt; i += 256) {
        unsigned e = ebuf[s0 + i];
        int dl = (e >> 17) & (BKT_SZ - 1);
        int r = atomicAdd(&cur2[dl], 1);
        ssorted[s0 + exc[dl] + r] = (int)(e & 0x1FFFF);
    }
}

// ---------------- GEMM1 (A from global, WB staged once): out = x @ W_enc -> f16 ----------

__device__ __forceinline__ void dev_gemm1_range(SmemU& sm, const float* __restrict__ x,
                                                const float* __restrict__ W,
                                                f16* __restrict__ out, int n,
                                                int t0, int tend, int stride) {
    if (t0 >= tend) return;
    f16* WB = sm.g1.WB;
    int tid = threadIdx.x;
    for (int i = tid; i < 4096; i += 256) {
        int k = i >> 4, c4 = (i & 15) * 4;
        float4 w = *(const float4*)&W[k * 64 + c4];
        int t = c4 >> 4, ks = k >> 5, q = (k & 31) >> 3, j = k & 7;
        int base = (((t * 8 + ks) * 64 + q * 16 + (c4 & 15)) * 8) + j;
        WB[base + 0]  = (f16)w.x;
        WB[base + 8]  = (f16)w.y;
        WB[base + 16] = (f16)w.z;
        WB[base + 24] = (f16)w.w;
    }
    __syncthreads();
    int lane = tid & 63, w = tid >> 6;
    int m = lane & 15, q = lane >> 4;
    for (int tile = t0; tile < tend; tile += stride) {
        int row0 = tile * 64;
        int row = row0 + 16 * w + m;
        const float* xr = &x[(size_t)(row < n ? row : 0) * 256];
        f32x4 acc[4];
#pragma unroll
        for (int t = 0; t < 4; t++) acc[t] = (f32x4){0.f, 0.f, 0.f, 0.f};
#pragma unroll
        for (int ks = 0; ks < 8; ks++) {
            float4 v0 = *(const float4*)&xr[32 * ks + 8 * q];
            float4 v1 = *(const float4*)&xr[32 * ks + 8 * q + 4];
            f16x8 a;
            a[0] = (f16)v0.x; a[1] = (f16)v0.y; a[2] = (f16)v0.z; a[3] = (f16)v0.w;
            a[4] = (f16)v1.x; a[5] = (f16)v1.y; a[6] = (f16)v1.z; a[7] = (f16)v1.w;
#pragma unroll
            for (int t = 0; t < 4; t++) {
                f16x8 bfr = *(const f16x8*)&WB[((t * 8 + ks) * 64 + lane) * 8];
                acc[t] = __builtin_amdgcn_mfma_f32_16x16x32_f16(a, bfr, acc[t], 0, 0, 0);
            }
        }
#pragma unroll
        for (int t = 0; t < 4; t++) {
#pragma unroll
            for (int r = 0; r < 4; r++) {
                int gr = row0 + 16 * w + 4 * q + r;
                if (gr < n) out[(size_t)gr * 64 + 16 * t + m] = (f16)acc[t][r];
            }
        }
    }
}

// ---------------- propagation node body ----------------

template <bool RELU_BIAS>
__device__ __forceinline__ void dev_prop_node(const f16* __restrict__ hpre,
                                              const int* __restrict__ row_ptr,
                                              const int* __restrict__ ssorted,
                                              const float* __restrict__ dinv,
                                              const float* __restrict__ bias,
                                              f16* __restrict__ out, int d, int lane) {
    int fg = lane & 15;
    int eg = lane >> 4;
    float dd = dinv[d];

    float ax = 0.f, ay = 0.f, az = 0.f, aw = 0.f;
    if (eg == 0) {
        half4 hv = *(const half4*)&hpre[(size_t)d * 64 + 4 * fg];
        ax = dd * (float)hv.x; ay = dd * (float)hv.y;
        az = dd * (float)hv.z; aw = dd * (float)hv.w;
    }

    int s0 = row_ptr[d], s1 = row_ptr[d + 1];
    for (int base = s0; base < s1; base += 64) {
        int j = base + lane;
        int sl = 0;
        float wl = 0.f;
        if (j < s1) { sl = ssorted[j]; wl = dinv[sl]; }
        int cnt = min(64, s1 - base);
        int i = 0;
        for (; i + 8 <= cnt; i += 8) {
            int e0 = i + eg, e1 = i + 4 + eg;
            int a0 = __shfl(sl, e0), a1 = __shfl(sl, e1);
            float w0 = __shfl(wl, e0), w1 = __shfl(wl, e1);
            half4 h0 = *(const half4*)&hpre[(size_t)a0 * 64 + 4 * fg];
            half4 h1 = *(const half4*)&hpre[(size_t)a1 * 64 + 4 * fg];
            ax += w0 * (float)h0.x; ay += w0 * (float)h0.y;
            az += w0 * (float)h0.z; aw += w0 * (float)h0.w;
            ax += w1 * (float)h1.x; ay += w1 * (float)h1.y;
            az += w1 * (float)h1.z; aw += w1 * (float)h1.w;
        }
        for (; i < cnt; i += 4) {
            int e = i + eg;
            int a = __shfl(sl, e);
            float w = __shfl(wl, e);
            if (e < cnt) {
                half4 hv = *(const half4*)&hpre[(size_t)a * 64 + 4 * fg];
                ax += w * (float)hv.x; ay += w * (float)hv.y;
                az += w * (float)hv.z; aw += w * (float)hv.w;
            }
        }
    }

    ax += __shfl_xor(ax, 16); ay += __shfl_xor(ay, 16);
    az += __shfl_xor(az, 16); aw += __shfl_xor(aw, 16);
    ax += __shfl_xor(ax, 32); ay += __shfl_xor(ay, 32);
    az += __shfl_xor(az, 32); aw += __shfl_xor(aw, 32);

    if (lane < 16) {
        float vx = dd * ax, vy = dd * ay, vz = dd * az, vw = dd * aw;
        if (RELU_BIAS) {
            float4 b = *(const float4*)&bias[4 * fg];
            vx = fmaxf(vx + b.x, 0.f); vy = fmaxf(vy + b.y, 0.f);
            vz = fmaxf(vz + b.z, 0.f); vw = fmaxf(vw + b.w, 0.f);
        }
        half4 hv;
        hv.x = (f16)vx; hv.y = (f16)vy; hv.z = (f16)vz; hv.w = (f16)vw;
        *(half4*)&out[(size_t)d * 64 + 4 * fg] = hv;
    }
}

// ---------------- middle (weights staged once, tiles grid-stride) ----------------

__device__ __forceinline__ void dev_mid_range(SmemU& sm, const f16* __restrict__ h1,
                                              const float* __restrict__ Wz, const float* __restrict__ bz,
                                              const float* __restrict__ Wd, const float* __restrict__ bd,
                                              const float* __restrict__ Wc, const float* __restrict__ bc,
                                              f16* __restrict__ hd_ws,
                                              float* __restrict__ z_out, float* __restrict__ pred_out,
                                              int n, int b, int tiles, int NB) {
    if (b >= tiles) return;
    int tid = threadIdx.x;
    for (int i = tid; i < 2048; i += 256) {
        int k = i >> 5, c = i & 31;
        int ks = k >> 5, q = (k >> 3) & 3, j = k & 7;
        int t = c >> 4, ln = q * 16 + (c & 15);
        sm.mid.WzB[((t * 2 + ks) * 64 + ln) * 8 + j] = (f16)Wz[i];
    }
    for (int i = tid; i < 2048; i += 256) {
        int k = i >> 6, c = i & 63;
        int q = k >> 3, j = k & 7;
        int t = c >> 4, ln = q * 16 + (c & 15);
        sm.mid.WdB[(t * 64 + ln) * 8 + j] = (f16)Wd[i];
    }
    if (tid < 96) sm.mid.Wcs[(tid / 3) * 4 + (tid % 3)] = Wc[tid];
    if (tid < 32) sm.mid.bzs[tid] = bz[tid];
    if (tid < 64) sm.mid.bds[tid] = bd[tid];
    if (tid < 3)  sm.mid.bcs[tid] = bc[tid];

    int lane = tid & 63, w = tid >> 6;
    int m = lane & 15, q = lane >> 4;

    for (int tile = b; tile < tiles; tile += NB) {
        int row0 = tile * 64;
        __syncthreads();
        for (int i = tid; i < 1024; i += 256) {
            int r = i >> 4, c4 = (i & 15) * 4;
            half4 hv = {0, 0, 0, 0};
            if (row0 + r < n) hv = *(const half4*)&h1[(size_t)(row0 + r) * 64 + c4];
            *(half4*)&sm.mid.Ah[r * 72 + c4] = hv;
        }
        __syncthreads();

        f32x4 za[2];
        za[0] = (f32x4){0.f, 0.f, 0.f, 0.f};
        za[1] = (f32x4){0.f, 0.f, 0.f, 0.f};
#pragma unroll
        for (int ks = 0; ks < 2; ks++) {
            f16x8 a = *(const f16x8*)&sm.mid.Ah[(16 * w + m) * 72 + 32 * ks + 8 * q];
#pragma unroll
            for (int t = 0; t < 2; t++) {
                f16x8 bfr = *(const f16x8*)&sm.mid.WzB[((t * 2 + ks) * 64 + lane) * 8];
                za[t] = __builtin_amdgcn_mfma_f32_16x16x32_f16(a, bfr, za[t], 0, 0, 0);
            }
        }
#pragma unroll
        for (int t = 0; t < 2; t++) {
            float bj = sm.mid.bzs[16 * t + m];
#pragma unroll
            for (int r = 0; r < 4; r++) {
                int node = 16 * w + 4 * q + r;
                float zv = za[t][r] + bj;
                sm.mid.Zh[node * 40 + 16 * t + m] = (f16)zv;
                if (row0 + node < n) z_out[(size_t)(row0 + node) * 32 + 16 * t + m] = zv;
            }
        }
        __syncthreads();

        f16x8 a2 = *(const f16x8*)&sm.mid.Zh[(16 * w + m) * 40 + 8 * q];
        f32x4 hb[4];
#pragma unroll
        for (int t = 0; t < 4; t++) {
            f16x8 bfr = *(const f16x8*)&sm.mid.WdB[(t * 64 + lane) * 8];
            f32x4 zero = (f32x4){0.f, 0.f, 0.f, 0.f};
            hb[t] = __builtin_amdgcn_mfma_f32_16x16x32_f16(a2, bfr, zero, 0, 0, 0);
        }
#pragma unroll
        for (int t = 0; t < 4; t++) {
            float bf = sm.mid.bds[16 * t + m];
#pragma unroll
            for (int r = 0; r < 4; r++) {
                int node = 16 * w + 4 * q + r;
                if (row0 + node < n)
                    hd_ws[(size_t)(row0 + node) * 64 + 16 * t + m] = (f16)fmaxf(hb[t][r] + bf, 0.f);
            }
        }

        if (tid < 64) {
            int node = tid;
            float pa = sm.mid.bcs[0], pb = sm.mid.bcs[1], pc = sm.mid.bcs[2];
            for (int k = 0; k < 32; k++) {
                float zv = (float)sm.mid.Zh[node * 40 + k];
                pa += zv * sm.mid.Wcs[k * 4 + 0];
                pb += zv * sm.mid.Wcs[k * 4 + 1];
                pc += zv * sm.mid.Wcs[k * 4 + 2];
            }
            if (row0 + node < n) {
                pred_out[(size_t)(row0 + node) * 3 + 0] = pa;
                pred_out[(size_t)(row0 + node) * 3 + 1] = pb;
                pred_out[(size_t)(row0 + node) * 3 + 2] = pc;
            }
        }
    }
}

// ---------------- GEMM5 (A from global, WB staged once) ----------------

__device__ __forceinline__ void dev_gemm5_range(SmemU& sm, const f16* __restrict__ A,
                                                const float* __restrict__ W,
                                                const float* __restrict__ bias,
                                                float* __restrict__ out, int n,
                                                int b, int tiles, int NB) {
    if (b >= tiles) return;
    f16* WB = sm.g5.WB;
    float* bs = sm.g5.bs;
    int tid = threadIdx.x;
    for (int i = tid; i < 4096; i += 256) {
        int k = i >> 6, c4 = (i & 63) * 4;
        float4 w = *(const float4*)&W[k * 256 + c4];
        int ks = k >> 5, q = (k >> 3) & 3, j = k & 7;
        int t = c4 >> 4;
        int base = ((t * 2 + ks) * 64 + q * 16 + (c4 & 15)) * 8 + j;
        WB[base + 0]  = (f16)w.x;
        WB[base + 8]  = (f16)w.y;
        WB[base + 16] = (f16)w.z;
        WB[base + 24] = (f16)w.w;
    }
    bs[tid] = bias[tid];
    __syncthreads();

    int lane = tid & 63, w = tid >> 6;
    int m = lane & 15, q = lane >> 4;

    for (int tile = b; tile < tiles; tile += NB) {
        int row0 = tile * 64;
        int row = row0 + 16 * w + m;
        const f16* ar = &A[(size_t)(row < n ? row : 0) * 64];
        f16x8 a0 = *(const f16x8*)&ar[8 * q];
        f16x8 a1 = *(const f16x8*)&ar[32 + 8 * q];

        int gr0 = row0 + 16 * w + 4 * q;
        bool full = (gr0 + 3 < n);
#pragma unroll 4
        for (int t = 0; t < 16; t++) {
            f32x4 acc = (f32x4){0.f, 0.f, 0.f, 0.f};
            f16x8 b0 = *(const f16x8*)&WB[((t * 2 + 0) * 64 + lane) * 8];
            acc = __builtin_amdgcn_mfma_f32_16x16x32_f16(a0, b0, acc, 0, 0, 0);
            f16x8 b1 = *(const f16x8*)&WB[((t * 2 + 1) * 64 + lane) * 8];
            acc = __builtin_amdgcn_mfma_f32_16x16x32_f16(a1, b1, acc, 0, 0, 0);
            float bf = bs[16 * t + m];
            if (full) {
#pragma unroll
                for (int r = 0; r < 4; r++)
                    out[(size_t)(gr0 + r) * 256 + 16 * t + m] = acc[r] + bf;
            } else {
#pragma unroll
                for (int r = 0; r < 4; r++)
                    if (gr0 + r < n) out[(size_t)(gr0 + r) * 256 + 16 * t + m] = acc[r] + bf;
            }
        }
    }
}

// ---------------- mega kernel ----------------

struct MegaArgs {
    const int *src, *dst;
    int E, n, nbin, nbk, NB, tiles, T1, T2;
    int *gcnt, *bcur;
    unsigned *ebuf;
    int *row_ptr;
    float *dinv;
    int *ssorted;
    const float *x, *Wenc, *benc, *Wz, *bz, *Wd, *bd, *Wc, *bc, *Wdec, *bdec;
    f16 *bufA, *bufB;
    float *out_xr, *out_z, *out_p;
};

__global__ __launch_bounds__(256, 4) void k_mega(MegaArgs a) {
    __shared__ SmemU sm;
    cg::grid_group grid = cg::this_grid();
    int b = blockIdx.x;
    int tid = threadIdx.x;
    int lane = tid & 63, wid = tid >> 6;

    // P1: bucket histogram || gemm1 tiles [0, T1)
    if (b < a.nbin) dev_bhist(sm, a.dst, a.E, a.nbk, a.gcnt, b);
    else dev_gemm1_range(sm, a.x, a.Wenc, a.bufA, a.n, b - a.nbin, a.T1, a.NB - a.nbin);
    grid.sync();

    // P2: binning || gemm1 tiles [T1, T2)
    if (b < a.nbin) dev_binA(sm, a.src, a.dst, a.E, a.gcnt, a.bcur, a.ebuf, b);
    else dev_gemm1_range(sm, a.x, a.Wenc, a.bufA, a.n, a.T1 + (b - a.nbin), a.T2, a.NB - a.nbin);
    grid.sync();

    // P3: per-bucket CSR || gemm1 tiles [T2, tiles)
    if (b < a.nbk) dev_csr(sm, a.ebuf, a.gcnt, a.n, a.E, a.row_ptr, a.dinv, a.ssorted, b);
    else dev_gemm1_range(sm, a.x, a.Wenc, a.bufA, a.n, a.T2 + (b - a.nbk), a.tiles, a.NB - a.nbk);
    grid.sync();

    // P4: prop1: bufB = relu(P bufA + b_enc)
    for (int d = b * 4 + wid; d < a.n; d += a.NB * 4)
        dev_prop_node<true>(a.bufA, a.row_ptr, a.ssorted, a.dinv, a.benc, a.bufB, d, lane);
    grid.sync();

    // P5: middle: z/pred out, hd -> bufA
    dev_mid_range(sm, a.bufB, a.Wz, a.bz, a.Wd, a.bd, a.Wc, a.bc,
                  a.bufA, a.out_z, a.out_p, a.n, b, a.tiles, a.NB);
    grid.sync();

    // P6: prop2: bufB = P bufA
    for (int d = b * 4 + wid; d < a.n; d += a.NB * 4)
        dev_prop_node<false>(a.bufA, a.row_ptr, a.ssorted, a.dinv, a.benc, a.bufB, d, lane);
    grid.sync();

    // P7: gemm5: x_recon = bufB @ W_dec + b_dec
    dev_gemm5_range(sm, a.bufB, a.Wdec, a.bdec, a.out_xr, a.n, b, a.tiles, a.NB);
}

// ---------------- launch ----------------

extern "C" void kernel_launch(void* const* d_in, const int* in_sizes, int n_in,
                              void* d_out, int out_size, void* d_ws, size_t ws_size,
                              hipStream_t stream) {
    const float* x    = (const float*)d_in[0];
    const int*   ei   = (const int*)d_in[1];
    const float* Wenc = (const float*)d_in[3];
    const float* benc = (const float*)d_in[4];
    const float* Wz   = (const float*)d_in[5];
    const float* bz   = (const float*)d_in[6];
    const float* Wd   = (const float*)d_in[7];
    const float* bd   = (const float*)d_in[8];
    const float* Wdec = (const float*)d_in[9];
    const float* bdec = (const float*)d_in[10];
    const float* Wc   = (const float*)d_in[11];
    const float* bc   = (const float*)d_in[12];

    int n = in_sizes[0] / 256;
    int E = in_sizes[1] / 2;

    int nbk = (n + BKT_SZ - 1) >> BKT_SH;
    int nbin = (E + EB - 1) / EB;

    char* w = (char*)d_ws;
    size_t off = 0;
    auto alloc = [&](size_t bytes) {
        void* p = w + off;
        off = (off + bytes + 255) & ~(size_t)255;
        return p;
    };
    int*      row_ptr = (int*)alloc(sizeof(int) * (n + 1));
    int*      ssorted = (int*)alloc(sizeof(int) * E);
    unsigned* ebuf    = (unsigned*)alloc(sizeof(unsigned) * E);
    float*    dinv    = (float*)alloc(sizeof(float) * n);
    int*      cnts    = (int*)alloc(sizeof(int) * 256);  // gcnt[128] + bcur[128]
    f16*      bufA    = (f16*)alloc(sizeof(f16) * (size_t)n * 64);  // h1pre -> hd
    f16*      bufB    = (f16*)alloc(sizeof(f16) * (size_t)n * 64);  // h1 -> p2
    (void)ws_size; (void)n_in; (void)out_size;

    float* out_xr = (float*)d_out;
    float* out_z  = out_xr + (size_t)n * 256;
    float* out_p  = out_z + (size_t)n * 32;

    static int g_nb = -1;
    if (g_nb < 0) {
        int occ = 0;
        hipOccupancyMaxActiveBlocksPerMultiprocessor(&occ, k_mega, 256, 0);
        if (occ < 1) occ = 1;
        g_nb = occ * 256;  // 256 CUs on MI355X
        if (g_nb > 2048) g_nb = 2048;
    }
    int NB = g_nb;

    int tiles = (n + 63) / 64;
    int T1 = tiles / 3;
    int T2 = (2 * tiles) / 3;

    hipMemsetAsync(cnts, 0, sizeof(int) * 256, stream);

    MegaArgs ma;
    ma.src = ei; ma.dst = ei + E;
    ma.E = E; ma.n = n; ma.nbin = nbin; ma.nbk = nbk; ma.NB = NB;
    ma.tiles = tiles; ma.T1 = T1; ma.T2 = T2;
    ma.gcnt = cnts; ma.bcur = cnts + 128;
    ma.ebuf = ebuf; ma.row_ptr = row_ptr; ma.dinv = dinv; ma.ssorted = ssorted;
    ma.x = x; ma.Wenc = Wenc; ma.benc = benc;
    ma.Wz = Wz; ma.bz = bz; ma.Wd = Wd; ma.bd = bd; ma.Wc = Wc; ma.bc = bc;
    ma.Wdec = Wdec; ma.bdec = bdec;
    ma.bufA = bufA; ma.bufB = bufB;
    ma.out_xr = out_xr; ma.out_z = out_z; ma.out_p = out_p;

    void* kargs[] = { &ma };
    hipLaunchCooperativeKernel(k_mega, dim3(NB), dim3(256), kargs, 0, stream);
}

// Round 7
// 249.187 us; speedup vs baseline: 2.9229x; 2.9229x over previous
//
#include <hip/hip_runtime.h>
#include <stdint.h>

typedef _Float16 f16;
typedef _Float16 half4 __attribute__((ext_vector_type(4)));
typedef _Float16 f16x8 __attribute__((ext_vector_type(8)));
typedef float f32x4 __attribute__((ext_vector_type(4)));

// ---------------- CSR build params: 256-node buckets ----------------

#define BKT_SH 8
#define BKT_SZ 256
#define EB 4096

struct __attribute__((aligned(16))) G1S { f16 WB[4 * 8 * 64 * 8]; f16 Ah[64 * 136]; };  // 49 KB
struct BinS { int h[BKT_SZ], segs[BKT_SZ], cur[BKT_SZ], s[256]; };
struct CsrS { int cnt[BKT_SZ], exc[BKT_SZ], cur2[BKT_SZ], p[256]; };
union __attribute__((aligned(16))) SmemU { G1S g1; BinS bin; CsrS csr; int bh[BKT_SZ]; };

// ---------------- CSR device bodies (256 threads) ----------------

__device__ __forceinline__ void dev_bhist(SmemU& sm, const int* __restrict__ dst, int E,
                                          int* __restrict__ gcnt, int bid) {
    int* h = sm.bh;
    int tid = threadIdx.x;
    h[tid] = 0;
    __syncthreads();
    int base = bid * EB;
    int end = min(base + EB, E);
    for (int i = base + tid; i < end; i += 256) atomicAdd(&h[dst[i] >> BKT_SH], 1);
    __syncthreads();
    if (h[tid]) atomicAdd(&gcnt[tid], h[tid]);
}

__device__ __forceinline__ void dev_binA(SmemU& sm, const int* __restrict__ src,
                                         const int* __restrict__ dst, int E,
                                         const int* __restrict__ gcnt, int* __restrict__ bcur,
                                         unsigned* __restrict__ ebuf, int bid) {
    int* h = sm.bin.h; int* segs = sm.bin.segs; int* cur = sm.bin.cur; int* s = sm.bin.s;
    int tid = threadIdx.x;
    h[tid] = 0; cur[tid] = 0;
    __syncthreads();
    int base = bid * EB;
    int end = min(base + EB, E);
    for (int i = base + tid; i < end; i += 256) atomicAdd(&h[dst[i] >> BKT_SH], 1);
    int v = gcnt[tid];
    s[tid] = v;
    __syncthreads();
    for (int o = 1; o < 256; o <<= 1) {
        int t = (tid >= o) ? s[tid - o] : 0;
        __syncthreads();
        s[tid] += t;
        __syncthreads();
    }
    segs[tid] = h[tid] ? (s[tid] - v) + atomicAdd(&bcur[tid], h[tid]) : 0;
    __syncthreads();
    for (int i = base + tid; i < end; i += 256) {
        int d = dst[i];
        int bk = d >> BKT_SH;
        int r = atomicAdd(&cur[bk], 1);
        ebuf[segs[bk] + r] = (unsigned)src[i] | ((unsigned)(d & (BKT_SZ - 1)) << 17);
    }
}

__device__ __forceinline__ void dev_csr(SmemU& sm, const unsigned* __restrict__ ebuf,
                                        const int* __restrict__ gcnt, int n, int E,
                                        int* __restrict__ row_ptr, float* __restrict__ dinv,
                                        int* __restrict__ ssorted, int b) {
    int* cnt = sm.csr.cnt; int* exc = sm.csr.exc; int* cur2 = sm.csr.cur2; int* p = sm.csr.p;
    int tid = threadIdx.x;
    int v = gcnt[tid];
    p[tid] = v;
    __syncthreads();
    for (int o = 1; o < 256; o <<= 1) {
        int t = (tid >= o) ? p[tid - o] : 0;
        __syncthreads();
        p[tid] += t;
        __syncthreads();
    }
    int scnt = gcnt[b];
    int s0 = p[b] - scnt;
    __syncthreads();
    if (b == 0 && tid == 0) row_ptr[n] = E;

    int d0 = b << BKT_SH;
    int ndl = min(BKT_SZ, n - d0);
    cnt[tid] = 0; cur2[tid] = 0;
    __syncthreads();
    for (int i = tid; i < scnt; i += 256)
        atomicAdd(&cnt[(ebuf[s0 + i] >> 17) & (BKT_SZ - 1)], 1);
    __syncthreads();
    int c = cnt[tid];
    p[tid] = c;
    __syncthreads();
    for (int o = 1; o < 256; o <<= 1) {
        int t = (tid >= o) ? p[tid - o] : 0;
        __syncthreads();
        p[tid] += t;
        __syncthreads();
    }
    int exc_t = p[tid] - c;
    exc[tid] = exc_t;
    if (tid < ndl) {
        row_ptr[d0 + tid] = s0 + exc_t;
        dinv[d0 + tid] = rsqrtf((float)(c + 1));  // +1 self loop
    }
    __syncthreads();
    for (int i = tid; i < scnt; i += 256) {
        unsigned e = ebuf[s0 + i];
        int dl = (e >> 17) & (BKT_SZ - 1);
        int r = atomicAdd(&cur2[dl], 1);
        ssorted[s0 + exc[dl] + r] = (int)(e & 0x1FFFF);
    }
}

// GEMM1 body: h1_pre[64 rows of tile][64] = x[.,256] @ W[256,64] -> f16
__device__ __forceinline__ void dev_gemm1(SmemU& sm, const float* __restrict__ x,
                                          const float* __restrict__ W, f16* __restrict__ out,
                                          int n, int tile) {
    f16* WB = sm.g1.WB;
    f16* Ah = sm.g1.Ah;
    int tid = threadIdx.x;
    int row0 = tile * 64;

    for (int i = tid; i < 4096; i += 256) {
        int k = i >> 4, c4 = (i & 15) * 4;
        float4 w = *(const float4*)&W[k * 64 + c4];
        int t = c4 >> 4, ks = k >> 5, q = (k & 31) >> 3, j = k & 7;
        int base = (((t * 8 + ks) * 64 + q * 16 + (c4 & 15)) * 8) + j;
        WB[base + 0]  = (f16)w.x;
        WB[base + 8]  = (f16)w.y;
        WB[base + 16] = (f16)w.z;
        WB[base + 24] = (f16)w.w;
    }

    int lane = tid & 63, w = tid >> 6;
    int m = lane & 15, q = lane >> 4;

    f32x4 acc[4];
#pragma unroll
    for (int t = 0; t < 4; t++) acc[t] = (f32x4){0.f, 0.f, 0.f, 0.f};

    for (int h = 0; h < 2; h++) {
        __syncthreads();
        for (int i = tid; i < 2048; i += 256) {
            int r = i >> 5, k4 = (i & 31) * 4;
            float4 v = {0.f, 0.f, 0.f, 0.f};
            if (row0 + r < n) v = *(const float4*)&x[(size_t)(row0 + r) * 256 + 128 * h + k4];
            half4 hv;
            hv.x = (f16)v.x; hv.y = (f16)v.y; hv.z = (f16)v.z; hv.w = (f16)v.w;
            *(half4*)&Ah[r * 136 + k4] = hv;
        }
        __syncthreads();
#pragma unroll
        for (int ksl = 0; ksl < 4; ksl++) {
            int ks = 4 * h + ksl;
            f16x8 a = *(const f16x8*)&Ah[(16 * w + m) * 136 + 32 * ksl + 8 * q];
#pragma unroll
            for (int t = 0; t < 4; t++) {
                f16x8 b = *(const f16x8*)&WB[((t * 8 + ks) * 64 + lane) * 8];
                acc[t] = __builtin_amdgcn_mfma_f32_16x16x32_f16(a, b, acc[t], 0, 0, 0);
            }
        }
    }

#pragma unroll
    for (int t = 0; t < 4; t++) {
#pragma unroll
        for (int r = 0; r < 4; r++) {
            int gr = row0 + 16 * w + 4 * q + r;
            if (gr < n) out[(size_t)gr * 64 + 16 * t + m] = (f16)acc[t][r];
        }
    }
}

// ---------------- fused phase kernels: CSR stage (blocks [0,nA)) + gemm1 slice ---------

__global__ __launch_bounds__(256) void k_p1(const int* __restrict__ dst, int E,
                                            int* __restrict__ gcnt,
                                            const float* __restrict__ x, const float* __restrict__ W,
                                            f16* __restrict__ out, int n, int nA, int tile0) {
    __shared__ SmemU sm;
    if ((int)blockIdx.x < nA) dev_bhist(sm, dst, E, gcnt, blockIdx.x);
    else dev_gemm1(sm, x, W, out, n, tile0 + (int)blockIdx.x - nA);
}

__global__ __launch_bounds__(256) void k_p2(const int* __restrict__ src, const int* __restrict__ dst,
                                            int E, const int* __restrict__ gcnt, int* __restrict__ bcur,
                                            unsigned* __restrict__ ebuf,
                                            const float* __restrict__ x, const float* __restrict__ W,
                                            f16* __restrict__ out, int n, int nA, int tile0) {
    __shared__ SmemU sm;
    if ((int)blockIdx.x < nA) dev_binA(sm, src, dst, E, gcnt, bcur, ebuf, blockIdx.x);
    else dev_gemm1(sm, x, W, out, n, tile0 + (int)blockIdx.x - nA);
}

__global__ __launch_bounds__(256) void k_p3(const unsigned* __restrict__ ebuf,
                                            const int* __restrict__ gcnt, int n, int E,
                                            int* __restrict__ row_ptr, float* __restrict__ dinv,
                                            int* __restrict__ ssorted,
                                            const float* __restrict__ x, const float* __restrict__ W,
                                            f16* __restrict__ out, int nA, int tile0) {
    __shared__ SmemU sm;
    if ((int)blockIdx.x < nA) dev_csr(sm, ebuf, gcnt, n, E, row_ptr, dinv, ssorted, blockIdx.x);
    else dev_gemm1(sm, x, W, out, n, tile0 + (int)blockIdx.x - nA);
}

// ---------------- propagation: out[d] = dinv[d]*(sum dinv[s]*h[s] + dinv[d]*h[d])
// Two nodes per 64-lane wave: each 32-lane half owns one node (2 independent gather
// chains per wave). Within a half: 2 edge-subgroups (eg = sl>>4) x 16 feature-lanes.

template <bool RELU_BIAS>
__global__ __launch_bounds__(256) void k_prop(const f16* __restrict__ hpre,
                                              const int* __restrict__ row_ptr,
                                              const int* __restrict__ ssorted,
                                              const float* __restrict__ dinv,
                                              const float* __restrict__ bias,
                                              f16* __restrict__ out, int n) {
    int tid = threadIdx.x;
    int lane = tid & 63, wid = tid >> 6;
    int hh = lane >> 5;   // half index within wave
    int sl = lane & 31;   // sub-lane within half
    int fg = sl & 15;     // features 4*fg .. 4*fg+3
    int eg = sl >> 4;     // edge subgroup 0..1
    int d = blockIdx.x * 8 + wid * 2 + hh;
    if (d >= n) return;
    float dd = dinv[d];

    float ax = 0.f, ay = 0.f, az = 0.f, aw = 0.f;
    if (eg == 0) {  // self loop in subgroup 0 of each half
        half4 hv = *(const half4*)&hpre[(size_t)d * 64 + 4 * fg];
        ax = dd * (float)hv.x; ay = dd * (float)hv.y;
        az = dd * (float)hv.z; aw = dd * (float)hv.w;
    }

    int s0 = row_ptr[d], s1 = row_ptr[d + 1];
    for (int base = s0; base < s1; base += 32) {
        int j = base + sl;
        int slv = 0;
        float wl = 0.f;
        if (j < s1) { slv = ssorted[j]; wl = dinv[slv]; }
        int cnt = min(32, s1 - base);
        int i = 0;
        for (; i + 8 <= cnt; i += 8) {  // 8 edges per iter, 4 independent loads/lane
            int e0 = i + eg, e1 = i + 2 + eg, e2 = i + 4 + eg, e3 = i + 6 + eg;
            int a0 = __shfl(slv, e0, 32), a1 = __shfl(slv, e1, 32);
            int a2 = __shfl(slv, e2, 32), a3 = __shfl(slv, e3, 32);
            float w0 = __shfl(wl, e0, 32), w1 = __shfl(wl, e1, 32);
            float w2 = __shfl(wl, e2, 32), w3 = __shfl(wl, e3, 32);
            half4 h0 = *(const half4*)&hpre[(size_t)a0 * 64 + 4 * fg];
            half4 h1 = *(const half4*)&hpre[(size_t)a1 * 64 + 4 * fg];
            half4 h2 = *(const half4*)&hpre[(size_t)a2 * 64 + 4 * fg];
            half4 h3 = *(const half4*)&hpre[(size_t)a3 * 64 + 4 * fg];
            ax += w0 * (float)h0.x; ay += w0 * (float)h0.y;
            az += w0 * (float)h0.z; aw += w0 * (float)h0.w;
            ax += w1 * (float)h1.x; ay += w1 * (float)h1.y;
            az += w1 * (float)h1.z; aw += w1 * (float)h1.w;
            ax += w2 * (float)h2.x; ay += w2 * (float)h2.y;
            az += w2 * (float)h2.z; aw += w2 * (float)h2.w;
            ax += w3 * (float)h3.x; ay += w3 * (float)h3.y;
            az += w3 * (float)h3.z; aw += w3 * (float)h3.w;
        }
        for (; i < cnt; i += 2) {  // tail: up to 2 edges, predicated
            int e = i + eg;
            int a = __shfl(slv, e, 32);
            float w = __shfl(wl, e, 32);
            if (e < cnt) {
                half4 hv = *(const half4*)&hpre[(size_t)a * 64 + 4 * fg];
                ax += w * (float)hv.x; ay += w * (float)hv.y;
                az += w * (float)hv.z; aw += w * (float)hv.w;
            }
        }
    }

    // reduce the 2 edge subgroups within each half (lanes differ in bit 4)
    ax += __shfl_xor(ax, 16, 32); ay += __shfl_xor(ay, 16, 32);
    az += __shfl_xor(az, 16, 32); aw += __shfl_xor(aw, 16, 32);

    if (sl < 16) {
        float vx = dd * ax, vy = dd * ay, vz = dd * az, vw = dd * aw;
        if (RELU_BIAS) {
            float4 b = *(const float4*)&bias[4 * fg];
            vx = fmaxf(vx + b.x, 0.f); vy = fmaxf(vy + b.y, 0.f);
            vz = fmaxf(vz + b.z, 0.f); vw = fmaxf(vw + b.w, 0.f);
        }
        half4 hv;
        hv.x = (f16)vx; hv.y = (f16)vy; hv.z = (f16)vz; hv.w = (f16)vw;
        *(half4*)&out[(size_t)d * 64 + 4 * fg] = hv;
    }
}

// ---------------- fused middle (MFMA): 64 nodes per block; h1/hd are f16 ----------------

#define MB 64
__global__ __launch_bounds__(256) void k_mid(const f16* __restrict__ h1,
                                             const float* __restrict__ Wz, const float* __restrict__ bz,
                                             const float* __restrict__ Wd, const float* __restrict__ bd,
                                             const float* __restrict__ Wc, const float* __restrict__ bc,
                                             f16* __restrict__ hd_ws,
                                             float* __restrict__ z_out, float* __restrict__ pred_out,
                                             int n) {
    __shared__ __attribute__((aligned(16))) f16 Ah[64 * 72];
    __shared__ __attribute__((aligned(16))) f16 Zh[64 * 40];
    __shared__ __attribute__((aligned(16))) f16 WzB[2 * 2 * 64 * 8];
    __shared__ __attribute__((aligned(16))) f16 WdB[4 * 64 * 8];
    __shared__ float Wcs[32 * 4];
    __shared__ float bzs[32], bds[64], bcs[4];
    int tid = threadIdx.x;
    int row0 = blockIdx.x * MB;

    for (int i = tid; i < 2048; i += 256) {
        int k = i >> 5, c = i & 31;
        int ks = k >> 5, q = (k >> 3) & 3, j = k & 7;
        int t = c >> 4, ln = q * 16 + (c & 15);
        WzB[((t * 2 + ks) * 64 + ln) * 8 + j] = (f16)Wz[i];
    }
    for (int i = tid; i < 2048; i += 256) {
        int k = i >> 6, c = i & 63;
        int q = k >> 3, j = k & 7;
        int t = c >> 4, ln = q * 16 + (c & 15);
        WdB[(t * 64 + ln) * 8 + j] = (f16)Wd[i];
    }
    if (tid < 96) Wcs[(tid / 3) * 4 + (tid % 3)] = Wc[tid];
    if (tid < 32) bzs[tid] = bz[tid];
    if (tid < 64) bds[tid] = bd[tid];
    if (tid < 3)  bcs[tid] = bc[tid];
    for (int i = tid; i < 1024; i += 256) {
        int r = i >> 4, c4 = (i & 15) * 4;
        half4 hv = {0, 0, 0, 0};
        if (row0 + r < n) hv = *(const half4*)&h1[(size_t)(row0 + r) * 64 + c4];
        *(half4*)&Ah[r * 72 + c4] = hv;
    }
    __syncthreads();

    int lane = tid & 63, w = tid >> 6;
    int m = lane & 15, q = lane >> 4;

    f32x4 za[2];
    za[0] = (f32x4){0.f, 0.f, 0.f, 0.f};
    za[1] = (f32x4){0.f, 0.f, 0.f, 0.f};
#pragma unroll
    for (int ks = 0; ks < 2; ks++) {
        f16x8 a = *(const f16x8*)&Ah[(16 * w + m) * 72 + 32 * ks + 8 * q];
#pragma unroll
        for (int t = 0; t < 2; t++) {
            f16x8 b = *(const f16x8*)&WzB[((t * 2 + ks) * 64 + lane) * 8];
            za[t] = __builtin_amdgcn_mfma_f32_16x16x32_f16(a, b, za[t], 0, 0, 0);
        }
    }
#pragma unroll
    for (int t = 0; t < 2; t++) {
        float bj = bzs[16 * t + m];
#pragma unroll
        for (int r = 0; r < 4; r++) {
            int node = 16 * w + 4 * q + r;
            float zv = za[t][r] + bj;
            Zh[node * 40 + 16 * t + m] = (f16)zv;
            if (row0 + node < n) z_out[(size_t)(row0 + node) * 32 + 16 * t + m] = zv;
        }
    }
    __syncthreads();

    f16x8 a2 = *(const f16x8*)&Zh[(16 * w + m) * 40 + 8 * q];
    f32x4 hb[4];
#pragma unroll
    for (int t = 0; t < 4; t++) {
        f16x8 b = *(const f16x8*)&WdB[(t * 64 + lane) * 8];
        f32x4 zero = (f32x4){0.f, 0.f, 0.f, 0.f};
        hb[t] = __builtin_amdgcn_mfma_f32_16x16x32_f16(a2, b, zero, 0, 0, 0);
    }
#pragma unroll
    for (int t = 0; t < 4; t++) {
        float bf = bds[16 * t + m];
#pragma unroll
        for (int r = 0; r < 4; r++) {
            int node = 16 * w + 4 * q + r;
            if (row0 + node < n)
                hd_ws[(size_t)(row0 + node) * 64 + 16 * t + m] = (f16)fmaxf(hb[t][r] + bf, 0.f);
        }
    }

    if (tid < 64) {
        int node = tid;
        float pa = bcs[0], pb = bcs[1], pc = bcs[2];
        for (int k = 0; k < 32; k++) {
            float zv = (float)Zh[node * 40 + k];
            pa += zv * Wcs[k * 4 + 0];
            pb += zv * Wcs[k * 4 + 1];
            pc += zv * Wcs[k * 4 + 2];
        }
        if (row0 + node < n) {
            pred_out[(size_t)(row0 + node) * 3 + 0] = pa;
            pred_out[(size_t)(row0 + node) * 3 + 1] = pb;
            pred_out[(size_t)(row0 + node) * 3 + 2] = pc;
        }
    }
}

// ---------------- GEMM5 (MFMA): x_recon[n,256] = p2[n,64] @ W_dec_gnn[64,256] + b ---------

#define G5_R 64
__global__ __launch_bounds__(256) void k_gemm5(const f16* __restrict__ A,
                                               const float* __restrict__ W,
                                               const float* __restrict__ bias,
                                               float* __restrict__ out, int n) {
    __shared__ __attribute__((aligned(16))) f16 WB[16 * 2 * 64 * 8];  // 32 KB
    __shared__ __attribute__((aligned(16))) f16 Ah[64 * 72];          // 9 KB
    __shared__ float bs[256];
    int tid = threadIdx.x;
    int row0 = blockIdx.x * G5_R;

    for (int i = tid; i < 4096; i += 256) {
        int k = i >> 6, c4 = (i & 63) * 4;
        float4 w = *(const float4*)&W[k * 256 + c4];
        int ks = k >> 5, q = (k >> 3) & 3, j = k & 7;
        int t = c4 >> 4;
        int base = ((t * 2 + ks) * 64 + q * 16 + (c4 & 15)) * 8 + j;
        WB[base + 0]  = (f16)w.x;
        WB[base + 8]  = (f16)w.y;
        WB[base + 16] = (f16)w.z;
        WB[base + 24] = (f16)w.w;
    }
    for (int i = tid; i < 1024; i += 256) {
        int r = i >> 4, c4 = (i & 15) * 4;
        half4 hv = {0, 0, 0, 0};
        if (row0 + r < n) hv = *(const half4*)&A[(size_t)(row0 + r) * 64 + c4];
        *(half4*)&Ah[r * 72 + c4] = hv;
    }
    bs[tid] = bias[tid];
    __syncthreads();

    int lane = tid & 63, w = tid >> 6;
    int m = lane & 15, q = lane >> 4;

    f16x8 a0 = *(const f16x8*)&Ah[(16 * w + m) * 72 + 0 + 8 * q];
    f16x8 a1 = *(const f16x8*)&Ah[(16 * w + m) * 72 + 32 + 8 * q];

    int gr0 = row0 + 16 * w + 4 * q;
    bool full = (gr0 + 3 < n);
#pragma unroll 4
    for (int t = 0; t < 16; t++) {
        f32x4 acc = (f32x4){0.f, 0.f, 0.f, 0.f};
        f16x8 b0 = *(const f16x8*)&WB[((t * 2 + 0) * 64 + lane) * 8];
        acc = __builtin_amdgcn_mfma_f32_16x16x32_f16(a0, b0, acc, 0, 0, 0);
        f16x8 b1 = *(const f16x8*)&WB[((t * 2 + 1) * 64 + lane) * 8];
        acc = __builtin_amdgcn_mfma_f32_16x16x32_f16(a1, b1, acc, 0, 0, 0);
        float bf = bs[16 * t + m];
        if (full) {
#pragma unroll
            for (int r = 0; r < 4; r++)
                out[(size_t)(gr0 + r) * 256 + 16 * t + m] = acc[r] + bf;
        } else {
#pragma unroll
            for (int r = 0; r < 4; r++)
                if (gr0 + r < n) out[(size_t)(gr0 + r) * 256 + 16 * t + m] = acc[r] + bf;
        }
    }
}

// ---------------- launch ----------------

extern "C" void kernel_launch(void* const* d_in, const int* in_sizes, int n_in,
                              void* d_out, int out_size, void* d_ws, size_t ws_size,
                              hipStream_t stream) {
    const float* x    = (const float*)d_in[0];
    const int*   ei   = (const int*)d_in[1];
    const float* Wenc = (const float*)d_in[3];
    const float* benc = (const float*)d_in[4];
    const float* Wz   = (const float*)d_in[5];
    const float* bz   = (const float*)d_in[6];
    const float* Wd   = (const float*)d_in[7];
    const float* bd   = (const float*)d_in[8];
    const float* Wdec = (const float*)d_in[9];
    const float* bdec = (const float*)d_in[10];
    const float* Wc   = (const float*)d_in[11];
    const float* bc   = (const float*)d_in[12];

    int n = in_sizes[0] / 256;
    int E = in_sizes[1] / 2;
    const int* src = ei;
    const int* dst = ei + E;

    int nbk = (n + BKT_SZ - 1) >> BKT_SH;
    int nbin = (E + EB - 1) / EB;

    char* w = (char*)d_ws;
    size_t off = 0;
    auto alloc = [&](size_t bytes) {
        void* p = w + off;
        off = (off + bytes + 255) & ~(size_t)255;
        return p;
    };
    int*      row_ptr = (int*)alloc(sizeof(int) * (n + 1));
    int*      ssorted = (int*)alloc(sizeof(int) * E);
    unsigned* ebuf    = (unsigned*)alloc(sizeof(unsigned) * E);
    float*    dinv    = (float*)alloc(sizeof(float) * n);
    int*      cnts    = (int*)alloc(sizeof(int) * 512);  // gcnt[256] + bcur[256]
    f16*      bufA    = (f16*)alloc(sizeof(f16) * (size_t)n * 64);  // h1pre -> hd
    f16*      bufB    = (f16*)alloc(sizeof(f16) * (size_t)n * 64);  // h1 -> p2
    (void)ws_size; (void)n_in; (void)out_size;

    int* gcnt = cnts;
    int* bcur = cnts + 256;

    float* out_xr = (float*)d_out;
    float* out_z  = out_xr + (size_t)n * 256;
    float* out_p  = out_z + (size_t)n * 32;

    // gemm1 tile split across the three CSR phases
    int tiles = (n + 63) / 64;
    int t1 = tiles / 3;
    int t2 = (2 * tiles) / 3;

    hipMemsetAsync(cnts, 0, sizeof(int) * 512, stream);

    // phase 1: bhist || gemm1 tiles [0, t1)
    k_p1<<<dim3(nbin + t1), dim3(256), 0, stream>>>(dst, E, gcnt, x, Wenc, bufA, n, nbin, 0);
    // phase 2: binA || gemm1 tiles [t1, t2)
    k_p2<<<dim3(nbin + (t2 - t1)), dim3(256), 0, stream>>>(src, dst, E, gcnt, bcur, ebuf,
                                                           x, Wenc, bufA, n, nbin, t1);
    // phase 3: csr || gemm1 tiles [t2, tiles)
    k_p3<<<dim3(nbk + (tiles - t2)), dim3(256), 0, stream>>>(ebuf, gcnt, n, E, row_ptr, dinv, ssorted,
                                                             x, Wenc, bufA, nbk, t2);

    // encoder gather: bufB = relu(P bufA + b_enc) (f16)
    k_prop<true><<<dim3((n + 7) / 8), dim3(256), 0, stream>>>(bufA, row_ptr, ssorted, dinv, benc, bufB, n);

    // middle: z (out), pred (out), hd -> bufA (f16)
    k_mid<<<dim3((n + MB - 1) / MB), dim3(256), 0, stream>>>(bufB, Wz, bz, Wd, bd, Wc, bc,
                                                             bufA, out_z, out_p, n);

    // decoder (reassociated): bufB = P bufA (f16) ; x_recon = bufB @ W_dec + b_dec
    k_prop<false><<<dim3((n + 7) / 8), dim3(256), 0, stream>>>(bufA, row_ptr, ssorted, dinv, benc, bufB, n);
    k_gemm5<<<dim3((n + G5_R - 1) / G5_R), dim3(256), 0, stream>>>(bufB, Wdec, bdec, out_xr, n);
}

// Round 8
// 248.755 us; speedup vs baseline: 2.9280x; 1.0017x over previous
//
#include <hip/hip_runtime.h>
#include <stdint.h>

typedef _Float16 f16;
typedef _Float16 half4 __attribute__((ext_vector_type(4)));
typedef _Float16 f16x8 __attribute__((ext_vector_type(8)));
typedef float f32x4 __attribute__((ext_vector_type(4)));

// ---------------- CSR build params: 256-node buckets ----------------

#define BKT_SH 8
#define BKT_SZ 256
#define EB 4096

struct __attribute__((aligned(16))) G1S { f16 WB[4 * 8 * 64 * 8]; f16 Ah[64 * 136]; };  // 49 KB
struct BinS { int h[BKT_SZ], segs[BKT_SZ], cur[BKT_SZ], s[256]; };
struct CsrS { int cnt[BKT_SZ], exc[BKT_SZ], cur2[BKT_SZ], p[256]; };
union __attribute__((aligned(16))) SmemU { G1S g1; BinS bin; CsrS csr; int bh[BKT_SZ]; };

// ---------------- CSR device bodies (256 threads) ----------------

__device__ __forceinline__ void dev_bhist(SmemU& sm, const int* __restrict__ dst, int E,
                                          int* __restrict__ gcnt, int bid) {
    int* h = sm.bh;
    int tid = threadIdx.x;
    h[tid] = 0;
    __syncthreads();
    int base = bid * EB;
    int end = min(base + EB, E);
    for (int i = base + tid; i < end; i += 256) atomicAdd(&h[dst[i] >> BKT_SH], 1);
    __syncthreads();
    if (h[tid]) atomicAdd(&gcnt[tid], h[tid]);
}

__device__ __forceinline__ void dev_binA(SmemU& sm, const int* __restrict__ src,
                                         const int* __restrict__ dst, int E,
                                         const int* __restrict__ gcnt, int* __restrict__ bcur,
                                         unsigned* __restrict__ ebuf, int bid) {
    int* h = sm.bin.h; int* segs = sm.bin.segs; int* cur = sm.bin.cur; int* s = sm.bin.s;
    int tid = threadIdx.x;
    h[tid] = 0; cur[tid] = 0;
    __syncthreads();
    int base = bid * EB;
    int end = min(base + EB, E);
    for (int i = base + tid; i < end; i += 256) atomicAdd(&h[dst[i] >> BKT_SH], 1);
    int v = gcnt[tid];
    s[tid] = v;
    __syncthreads();
    for (int o = 1; o < 256; o <<= 1) {
        int t = (tid >= o) ? s[tid - o] : 0;
        __syncthreads();
        s[tid] += t;
        __syncthreads();
    }
    segs[tid] = h[tid] ? (s[tid] - v) + atomicAdd(&bcur[tid], h[tid]) : 0;
    __syncthreads();
    for (int i = base + tid; i < end; i += 256) {
        int d = dst[i];
        int bk = d >> BKT_SH;
        int r = atomicAdd(&cur[bk], 1);
        ebuf[segs[bk] + r] = (unsigned)src[i] | ((unsigned)(d & (BKT_SZ - 1)) << 17);
    }
}

__device__ __forceinline__ void dev_csr(SmemU& sm, const unsigned* __restrict__ ebuf,
                                        const int* __restrict__ gcnt, int n, int E,
                                        int* __restrict__ row_ptr, float* __restrict__ dinv,
                                        int* __restrict__ ssorted, int b) {
    int* cnt = sm.csr.cnt; int* exc = sm.csr.exc; int* cur2 = sm.csr.cur2; int* p = sm.csr.p;
    int tid = threadIdx.x;
    int v = gcnt[tid];
    p[tid] = v;
    __syncthreads();
    for (int o = 1; o < 256; o <<= 1) {
        int t = (tid >= o) ? p[tid - o] : 0;
        __syncthreads();
        p[tid] += t;
        __syncthreads();
    }
    int scnt = gcnt[b];
    int s0 = p[b] - scnt;
    __syncthreads();
    if (b == 0 && tid == 0) row_ptr[n] = E;

    int d0 = b << BKT_SH;
    int ndl = min(BKT_SZ, n - d0);
    cnt[tid] = 0; cur2[tid] = 0;
    __syncthreads();
    for (int i = tid; i < scnt; i += 256)
        atomicAdd(&cnt[(ebuf[s0 + i] >> 17) & (BKT_SZ - 1)], 1);
    __syncthreads();
    int c = cnt[tid];
    p[tid] = c;
    __syncthreads();
    for (int o = 1; o < 256; o <<= 1) {
        int t = (tid >= o) ? p[tid - o] : 0;
        __syncthreads();
        p[tid] += t;
        __syncthreads();
    }
    int exc_t = p[tid] - c;
    exc[tid] = exc_t;
    if (tid < ndl) {
        row_ptr[d0 + tid] = s0 + exc_t;
        dinv[d0 + tid] = rsqrtf((float)(c + 1));  // +1 self loop
    }
    __syncthreads();
    for (int i = tid; i < scnt; i += 256) {
        unsigned e = ebuf[s0 + i];
        int dl = (e >> 17) & (BKT_SZ - 1);
        int r = atomicAdd(&cur2[dl], 1);
        ssorted[s0 + exc[dl] + r] = (int)(e & 0x1FFFF);
    }
}

// GEMM1 body: h1_pre[64 rows of tile][64] = x[.,256] @ W[256,64] -> f16
__device__ __forceinline__ void dev_gemm1(SmemU& sm, const float* __restrict__ x,
                                          const float* __restrict__ W, f16* __restrict__ out,
                                          int n, int tile) {
    f16* WB = sm.g1.WB;
    f16* Ah = sm.g1.Ah;
    int tid = threadIdx.x;
    int row0 = tile * 64;

    for (int i = tid; i < 4096; i += 256) {
        int k = i >> 4, c4 = (i & 15) * 4;
        float4 w = *(const float4*)&W[k * 64 + c4];
        int t = c4 >> 4, ks = k >> 5, q = (k & 31) >> 3, j = k & 7;
        int base = (((t * 8 + ks) * 64 + q * 16 + (c4 & 15)) * 8) + j;
        WB[base + 0]  = (f16)w.x;
        WB[base + 8]  = (f16)w.y;
        WB[base + 16] = (f16)w.z;
        WB[base + 24] = (f16)w.w;
    }

    int lane = tid & 63, w = tid >> 6;
    int m = lane & 15, q = lane >> 4;

    f32x4 acc[4];
#pragma unroll
    for (int t = 0; t < 4; t++) acc[t] = (f32x4){0.f, 0.f, 0.f, 0.f};

    for (int h = 0; h < 2; h++) {
        __syncthreads();
        for (int i = tid; i < 2048; i += 256) {
            int r = i >> 5, k4 = (i & 31) * 4;
            float4 v = {0.f, 0.f, 0.f, 0.f};
            if (row0 + r < n) v = *(const float4*)&x[(size_t)(row0 + r) * 256 + 128 * h + k4];
            half4 hv;
            hv.x = (f16)v.x; hv.y = (f16)v.y; hv.z = (f16)v.z; hv.w = (f16)v.w;
            *(half4*)&Ah[r * 136 + k4] = hv;
        }
        __syncthreads();
#pragma unroll
        for (int ksl = 0; ksl < 4; ksl++) {
            int ks = 4 * h + ksl;
            f16x8 a = *(const f16x8*)&Ah[(16 * w + m) * 136 + 32 * ksl + 8 * q];
#pragma unroll
            for (int t = 0; t < 4; t++) {
                f16x8 b = *(const f16x8*)&WB[((t * 8 + ks) * 64 + lane) * 8];
                acc[t] = __builtin_amdgcn_mfma_f32_16x16x32_f16(a, b, acc[t], 0, 0, 0);
            }
        }
    }

#pragma unroll
    for (int t = 0; t < 4; t++) {
#pragma unroll
        for (int r = 0; r < 4; r++) {
            int gr = row0 + 16 * w + 4 * q + r;
            if (gr < n) out[(size_t)gr * 64 + 16 * t + m] = (f16)acc[t][r];
        }
    }
}

// ---------------- fused phase kernels: CSR stage (blocks [0,nA)) + gemm1 slice ---------

__global__ __launch_bounds__(256) void k_p1(const int* __restrict__ dst, int E,
                                            int* __restrict__ gcnt,
                                            const float* __restrict__ x, const float* __restrict__ W,
                                            f16* __restrict__ out, int n, int nA, int tile0) {
    __shared__ SmemU sm;
    if ((int)blockIdx.x < nA) dev_bhist(sm, dst, E, gcnt, blockIdx.x);
    else dev_gemm1(sm, x, W, out, n, tile0 + (int)blockIdx.x - nA);
}

__global__ __launch_bounds__(256) void k_p2(const int* __restrict__ src, const int* __restrict__ dst,
                                            int E, const int* __restrict__ gcnt, int* __restrict__ bcur,
                                            unsigned* __restrict__ ebuf,
                                            const float* __restrict__ x, const float* __restrict__ W,
                                            f16* __restrict__ out, int n, int nA, int tile0) {
    __shared__ SmemU sm;
    if ((int)blockIdx.x < nA) dev_binA(sm, src, dst, E, gcnt, bcur, ebuf, blockIdx.x);
    else dev_gemm1(sm, x, W, out, n, tile0 + (int)blockIdx.x - nA);
}

__global__ __launch_bounds__(256) void k_p3(const unsigned* __restrict__ ebuf,
                                            const int* __restrict__ gcnt, int n, int E,
                                            int* __restrict__ row_ptr, float* __restrict__ dinv,
                                            int* __restrict__ ssorted,
                                            const float* __restrict__ x, const float* __restrict__ W,
                                            f16* __restrict__ out, int nA, int tile0) {
    __shared__ SmemU sm;
    if ((int)blockIdx.x < nA) dev_csr(sm, ebuf, gcnt, n, E, row_ptr, dinv, ssorted, blockIdx.x);
    else dev_gemm1(sm, x, W, out, n, tile0 + (int)blockIdx.x - nA);
}

// ---------------- propagation: out[d] = dinv[d]*(sum dinv[s]*h[s] + dinv[d]*h[d])
// One node per 16-lane group (4 independent gather chains per wave). Each lane owns
// 4 features for ALL edges of its node -> no cross-lane reduction. Inner loop is an
// unconditional 8-deep unroll: out-of-range lanes carry wl=0, and 0*v==0 keeps the
// sum exact (slv=0 -> benign cached read of row 0).

template <bool RELU_BIAS>
__global__ __launch_bounds__(256) void k_prop(const f16* __restrict__ hpre,
                                              const int* __restrict__ row_ptr,
                                              const int* __restrict__ ssorted,
                                              const float* __restrict__ dinv,
                                              const float* __restrict__ bias,
                                              f16* __restrict__ out, int n) {
    int tid = threadIdx.x;
    int lane = tid & 63, wid = tid >> 6;
    int g = lane >> 4;    // node-group within wave (0..3)
    int fg = lane & 15;   // feature group: features 4*fg .. 4*fg+3
    int d = blockIdx.x * 16 + wid * 4 + g;
    if (d >= n) return;
    float dd = dinv[d];

    // self loop (every lane owns distinct features)
    half4 hs = *(const half4*)&hpre[(size_t)d * 64 + 4 * fg];
    float ax = dd * (float)hs.x, ay = dd * (float)hs.y;
    float az = dd * (float)hs.z, aw = dd * (float)hs.w;

    int s0 = row_ptr[d], s1 = row_ptr[d + 1];
    for (int base = s0; base < s1; base += 16) {
        int j = base + fg;
        int slv = 0;
        float wl = 0.f;
        if (j < s1) { slv = ssorted[j]; wl = dinv[slv]; }
        int cnt = min(16, s1 - base);
        for (int i = 0; i < cnt; i += 8) {
            int a0 = __shfl(slv, i + 0, 16), a1 = __shfl(slv, i + 1, 16);
            int a2 = __shfl(slv, i + 2, 16), a3 = __shfl(slv, i + 3, 16);
            int a4 = __shfl(slv, i + 4, 16), a5 = __shfl(slv, i + 5, 16);
            int a6 = __shfl(slv, i + 6, 16), a7 = __shfl(slv, i + 7, 16);
            float w0 = __shfl(wl, i + 0, 16), w1 = __shfl(wl, i + 1, 16);
            float w2 = __shfl(wl, i + 2, 16), w3 = __shfl(wl, i + 3, 16);
            float w4 = __shfl(wl, i + 4, 16), w5 = __shfl(wl, i + 5, 16);
            float w6 = __shfl(wl, i + 6, 16), w7 = __shfl(wl, i + 7, 16);
            half4 h0 = *(const half4*)&hpre[(size_t)a0 * 64 + 4 * fg];
            half4 h1 = *(const half4*)&hpre[(size_t)a1 * 64 + 4 * fg];
            half4 h2 = *(const half4*)&hpre[(size_t)a2 * 64 + 4 * fg];
            half4 h3 = *(const half4*)&hpre[(size_t)a3 * 64 + 4 * fg];
            half4 h4 = *(const half4*)&hpre[(size_t)a4 * 64 + 4 * fg];
            half4 h5 = *(const half4*)&hpre[(size_t)a5 * 64 + 4 * fg];
            half4 h6 = *(const half4*)&hpre[(size_t)a6 * 64 + 4 * fg];
            half4 h7 = *(const half4*)&hpre[(size_t)a7 * 64 + 4 * fg];
            ax += w0 * (float)h0.x; ay += w0 * (float)h0.y;
            az += w0 * (float)h0.z; aw += w0 * (float)h0.w;
            ax += w1 * (float)h1.x; ay += w1 * (float)h1.y;
            az += w1 * (float)h1.z; aw += w1 * (float)h1.w;
            ax += w2 * (float)h2.x; ay += w2 * (float)h2.y;
            az += w2 * (float)h2.z; aw += w2 * (float)h2.w;
            ax += w3 * (float)h3.x; ay += w3 * (float)h3.y;
            az += w3 * (float)h3.z; aw += w3 * (float)h3.w;
            ax += w4 * (float)h4.x; ay += w4 * (float)h4.y;
            az += w4 * (float)h4.z; aw += w4 * (float)h4.w;
            ax += w5 * (float)h5.x; ay += w5 * (float)h5.y;
            az += w5 * (float)h5.z; aw += w5 * (float)h5.w;
            ax += w6 * (float)h6.x; ay += w6 * (float)h6.y;
            az += w6 * (float)h6.z; aw += w6 * (float)h6.w;
            ax += w7 * (float)h7.x; ay += w7 * (float)h7.y;
            az += w7 * (float)h7.z; aw += w7 * (float)h7.w;
        }
    }

    float vx = dd * ax, vy = dd * ay, vz = dd * az, vw = dd * aw;
    if (RELU_BIAS) {
        float4 b = *(const float4*)&bias[4 * fg];
        vx = fmaxf(vx + b.x, 0.f); vy = fmaxf(vy + b.y, 0.f);
        vz = fmaxf(vz + b.z, 0.f); vw = fmaxf(vw + b.w, 0.f);
    }
    half4 hv;
    hv.x = (f16)vx; hv.y = (f16)vy; hv.z = (f16)vz; hv.w = (f16)vw;
    *(half4*)&out[(size_t)d * 64 + 4 * fg] = hv;
}

// ---------------- fused middle (MFMA): 64 nodes per block; h1/hd are f16 ----------------

#define MB 64
__global__ __launch_bounds__(256) void k_mid(const f16* __restrict__ h1,
                                             const float* __restrict__ Wz, const float* __restrict__ bz,
                                             const float* __restrict__ Wd, const float* __restrict__ bd,
                                             const float* __restrict__ Wc, const float* __restrict__ bc,
                                             f16* __restrict__ hd_ws,
                                             float* __restrict__ z_out, float* __restrict__ pred_out,
                                             int n) {
    __shared__ __attribute__((aligned(16))) f16 Ah[64 * 72];
    __shared__ __attribute__((aligned(16))) f16 Zh[64 * 40];
    __shared__ __attribute__((aligned(16))) f16 WzB[2 * 2 * 64 * 8];
    __shared__ __attribute__((aligned(16))) f16 WdB[4 * 64 * 8];
    __shared__ float Wcs[32 * 4];
    __shared__ float bzs[32], bds[64], bcs[4];
    int tid = threadIdx.x;
    int row0 = blockIdx.x * MB;

    for (int i = tid; i < 2048; i += 256) {
        int k = i >> 5, c = i & 31;
        int ks = k >> 5, q = (k >> 3) & 3, j = k & 7;
        int t = c >> 4, ln = q * 16 + (c & 15);
        WzB[((t * 2 + ks) * 64 + ln) * 8 + j] = (f16)Wz[i];
    }
    for (int i = tid; i < 2048; i += 256) {
        int k = i >> 6, c = i & 63;
        int q = k >> 3, j = k & 7;
        int t = c >> 4, ln = q * 16 + (c & 15);
        WdB[(t * 64 + ln) * 8 + j] = (f16)Wd[i];
    }
    if (tid < 96) Wcs[(tid / 3) * 4 + (tid % 3)] = Wc[tid];
    if (tid < 32) bzs[tid] = bz[tid];
    if (tid < 64) bds[tid] = bd[tid];
    if (tid < 3)  bcs[tid] = bc[tid];
    for (int i = tid; i < 1024; i += 256) {
        int r = i >> 4, c4 = (i & 15) * 4;
        half4 hv = {0, 0, 0, 0};
        if (row0 + r < n) hv = *(const half4*)&h1[(size_t)(row0 + r) * 64 + c4];
        *(half4*)&Ah[r * 72 + c4] = hv;
    }
    __syncthreads();

    int lane = tid & 63, w = tid >> 6;
    int m = lane & 15, q = lane >> 4;

    f32x4 za[2];
    za[0] = (f32x4){0.f, 0.f, 0.f, 0.f};
    za[1] = (f32x4){0.f, 0.f, 0.f, 0.f};
#pragma unroll
    for (int ks = 0; ks < 2; ks++) {
        f16x8 a = *(const f16x8*)&Ah[(16 * w + m) * 72 + 32 * ks + 8 * q];
#pragma unroll
        for (int t = 0; t < 2; t++) {
            f16x8 b = *(const f16x8*)&WzB[((t * 2 + ks) * 64 + lane) * 8];
            za[t] = __builtin_amdgcn_mfma_f32_16x16x32_f16(a, b, za[t], 0, 0, 0);
        }
    }
#pragma unroll
    for (int t = 0; t < 2; t++) {
        float bj = bzs[16 * t + m];
#pragma unroll
        for (int r = 0; r < 4; r++) {
            int node = 16 * w + 4 * q + r;
            float zv = za[t][r] + bj;
            Zh[node * 40 + 16 * t + m] = (f16)zv;
            if (row0 + node < n) z_out[(size_t)(row0 + node) * 32 + 16 * t + m] = zv;
        }
    }
    __syncthreads();

    f16x8 a2 = *(const f16x8*)&Zh[(16 * w + m) * 40 + 8 * q];
    f32x4 hb[4];
#pragma unroll
    for (int t = 0; t < 4; t++) {
        f16x8 b = *(const f16x8*)&WdB[(t * 64 + lane) * 8];
        f32x4 zero = (f32x4){0.f, 0.f, 0.f, 0.f};
        hb[t] = __builtin_amdgcn_mfma_f32_16x16x32_f16(a2, b, zero, 0, 0, 0);
    }
#pragma unroll
    for (int t = 0; t < 4; t++) {
        float bf = bds[16 * t + m];
#pragma unroll
        for (int r = 0; r < 4; r++) {
            int node = 16 * w + 4 * q + r;
            if (row0 + node < n)
                hd_ws[(size_t)(row0 + node) * 64 + 16 * t + m] = (f16)fmaxf(hb[t][r] + bf, 0.f);
        }
    }

    if (tid < 64) {
        int node = tid;
        float pa = bcs[0], pb = bcs[1], pc = bcs[2];
        for (int k = 0; k < 32; k++) {
            float zv = (float)Zh[node * 40 + k];
            pa += zv * Wcs[k * 4 + 0];
            pb += zv * Wcs[k * 4 + 1];
            pc += zv * Wcs[k * 4 + 2];
        }
        if (row0 + node < n) {
            pred_out[(size_t)(row0 + node) * 3 + 0] = pa;
            pred_out[(size_t)(row0 + node) * 3 + 1] = pb;
            pred_out[(size_t)(row0 + node) * 3 + 2] = pc;
        }
    }
}

// ---------------- GEMM5 (MFMA): x_recon[n,256] = p2[n,64] @ W_dec_gnn[64,256] + b ---------

#define G5_R 64
__global__ __launch_bounds__(256) void k_gemm5(const f16* __restrict__ A,
                                               const float* __restrict__ W,
                                               const float* __restrict__ bias,
                                               float* __restrict__ out, int n) {
    __shared__ __attribute__((aligned(16))) f16 WB[16 * 2 * 64 * 8];  // 32 KB
    __shared__ __attribute__((aligned(16))) f16 Ah[64 * 72];          // 9 KB
    __shared__ float bs[256];
    int tid = threadIdx.x;
    int row0 = blockIdx.x * G5_R;

    for (int i = tid; i < 4096; i += 256) {
        int k = i >> 6, c4 = (i & 63) * 4;
        float4 w = *(const float4*)&W[k * 256 + c4];
        int ks = k >> 5, q = (k >> 3) & 3, j = k & 7;
        int t = c4 >> 4;
        int base = ((t * 2 + ks) * 64 + q * 16 + (c4 & 15)) * 8 + j;
        WB[base + 0]  = (f16)w.x;
        WB[base + 8]  = (f16)w.y;
        WB[base + 16] = (f16)w.z;
        WB[base + 24] = (f16)w.w;
    }
    for (int i = tid; i < 1024; i += 256) {
        int r = i >> 4, c4 = (i & 15) * 4;
        half4 hv = {0, 0, 0, 0};
        if (row0 + r < n) hv = *(const half4*)&A[(size_t)(row0 + r) * 64 + c4];
        *(half4*)&Ah[r * 72 + c4] = hv;
    }
    bs[tid] = bias[tid];
    __syncthreads();

    int lane = tid & 63, w = tid >> 6;
    int m = lane & 15, q = lane >> 4;

    f16x8 a0 = *(const f16x8*)&Ah[(16 * w + m) * 72 + 0 + 8 * q];
    f16x8 a1 = *(const f16x8*)&Ah[(16 * w + m) * 72 + 32 + 8 * q];

    int gr0 = row0 + 16 * w + 4 * q;
    bool full = (gr0 + 3 < n);
#pragma unroll 4
    for (int t = 0; t < 16; t++) {
        f32x4 acc = (f32x4){0.f, 0.f, 0.f, 0.f};
        f16x8 b0 = *(const f16x8*)&WB[((t * 2 + 0) * 64 + lane) * 8];
        acc = __builtin_amdgcn_mfma_f32_16x16x32_f16(a0, b0, acc, 0, 0, 0);
        f16x8 b1 = *(const f16x8*)&WB[((t * 2 + 1) * 64 + lane) * 8];
        acc = __builtin_amdgcn_mfma_f32_16x16x32_f16(a1, b1, acc, 0, 0, 0);
        float bf = bs[16 * t + m];
        if (full) {
#pragma unroll
            for (int r = 0; r < 4; r++)
                out[(size_t)(gr0 + r) * 256 + 16 * t + m] = acc[r] + bf;
        } else {
#pragma unroll
            for (int r = 0; r < 4; r++)
                if (gr0 + r < n) out[(size_t)(gr0 + r) * 256 + 16 * t + m] = acc[r] + bf;
        }
    }
}

// ---------------- launch ----------------

extern "C" void kernel_launch(void* const* d_in, const int* in_sizes, int n_in,
                              void* d_out, int out_size, void* d_ws, size_t ws_size,
                              hipStream_t stream) {
    const float* x    = (const float*)d_in[0];
    const int*   ei   = (const int*)d_in[1];
    const float* Wenc = (const float*)d_in[3];
    const float* benc = (const float*)d_in[4];
    const float* Wz   = (const float*)d_in[5];
    const float* bz   = (const float*)d_in[6];
    const float* Wd   = (const float*)d_in[7];
    const float* bd   = (const float*)d_in[8];
    const float* Wdec = (const float*)d_in[9];
    const float* bdec = (const float*)d_in[10];
    const float* Wc   = (const float*)d_in[11];
    const float* bc   = (const float*)d_in[12];

    int n = in_sizes[0] / 256;
    int E = in_sizes[1] / 2;
    const int* src = ei;
    const int* dst = ei + E;

    int nbk = (n + BKT_SZ - 1) >> BKT_SH;
    int nbin = (E + EB - 1) / EB;

    char* w = (char*)d_ws;
    size_t off = 0;
    auto alloc = [&](size_t bytes) {
        void* p = w + off;
        off = (off + bytes + 255) & ~(size_t)255;
        return p;
    };
    int*      row_ptr = (int*)alloc(sizeof(int) * (n + 1));
    int*      ssorted = (int*)alloc(sizeof(int) * E);
    unsigned* ebuf    = (unsigned*)alloc(sizeof(unsigned) * E);
    float*    dinv    = (float*)alloc(sizeof(float) * n);
    int*      cnts    = (int*)alloc(sizeof(int) * 512);  // gcnt[256] + bcur[256]
    f16*      bufA    = (f16*)alloc(sizeof(f16) * (size_t)n * 64);  // h1pre -> hd
    f16*      bufB    = (f16*)alloc(sizeof(f16) * (size_t)n * 64);  // h1 -> p2
    (void)ws_size; (void)n_in; (void)out_size;

    int* gcnt = cnts;
    int* bcur = cnts + 256;

    float* out_xr = (float*)d_out;
    float* out_z  = out_xr + (size_t)n * 256;
    float* out_p  = out_z + (size_t)n * 32;

    // gemm1 tile split across the three CSR phases
    int tiles = (n + 63) / 64;
    int t1 = tiles / 3;
    int t2 = (2 * tiles) / 3;

    hipMemsetAsync(cnts, 0, sizeof(int) * 512, stream);

    // phase 1: bhist || gemm1 tiles [0, t1)
    k_p1<<<dim3(nbin + t1), dim3(256), 0, stream>>>(dst, E, gcnt, x, Wenc, bufA, n, nbin, 0);
    // phase 2: binA || gemm1 tiles [t1, t2)
    k_p2<<<dim3(nbin + (t2 - t1)), dim3(256), 0, stream>>>(src, dst, E, gcnt, bcur, ebuf,
                                                           x, Wenc, bufA, n, nbin, t1);
    // phase 3: csr || gemm1 tiles [t2, tiles)
    k_p3<<<dim3(nbk + (tiles - t2)), dim3(256), 0, stream>>>(ebuf, gcnt, n, E, row_ptr, dinv, ssorted,
                                                             x, Wenc, bufA, nbk, t2);

    // encoder gather: bufB = relu(P bufA + b_enc) (f16)
    k_prop<true><<<dim3((n + 15) / 16), dim3(256), 0, stream>>>(bufA, row_ptr, ssorted, dinv, benc, bufB, n);

    // middle: z (out), pred (out), hd -> bufA (f16)
    k_mid<<<dim3((n + MB - 1) / MB), dim3(256), 0, stream>>>(bufB, Wz, bz, Wd, bd, Wc, bc,
                                                             bufA, out_z, out_p, n);

    // decoder (reassociated): bufB = P bufA (f16) ; x_recon = bufB @ W_dec + b_dec
    k_prop<false><<<dim3((n + 15) / 16), dim3(256), 0, stream>>>(bufA, row_ptr, ssorted, dinv, benc, bufB, n);
    k_gemm5<<<dim3((n + G5_R - 1) / G5_R), dim3(256), 0, stream>>>(bufB, Wdec, bdec, out_xr, n);
}

// Round 9
// 226.836 us; speedup vs baseline: 3.2110x; 1.0966x over previous
//
#include <hip/hip_runtime.h>
#include <stdint.h>

typedef _Float16 f16;
typedef _Float16 half4 __attribute__((ext_vector_type(4)));
typedef _Float16 f16x8 __attribute__((ext_vector_type(8)));
typedef float f32x4 __attribute__((ext_vector_type(4)));

// ---------------- CSR build params: 256-node buckets, bucket-strided ebuf ----------------

#define BKT_SH 8
#define BKT_SZ 256
#define EB 4096
#define BCAP 16384  // per-bucket capacity (uniform-random E=800k over 196 buckets -> max ~4.4k)

struct __attribute__((aligned(16))) G1S { f16 WB[4 * 8 * 64 * 8]; f16 Ah[64 * 136]; };  // 49 KB
struct BinS { int h[256], segs[256], cur[256]; };
struct CsrS { int cnt[256], exc[256], cur2[256], p[256]; };
union __attribute__((aligned(16))) SmemU { G1S g1; BinS bin; CsrS csr; };

// ---------------- CSR device bodies (256 threads) ----------------

// single-pass binning: per-block LDS histogram, reserve per-bucket chunk via global atomic,
// scatter into bucket-strided ebuf[bk*BCAP + ...]
__device__ __forceinline__ void dev_binA2(SmemU& sm, const int* __restrict__ src,
                                          const int* __restrict__ dst, int E,
                                          int* __restrict__ bcur, unsigned* __restrict__ ebuf,
                                          int bid) {
    int* h = sm.bin.h; int* segs = sm.bin.segs; int* cur = sm.bin.cur;
    int tid = threadIdx.x;
    h[tid] = 0; cur[tid] = 0;
    __syncthreads();
    int base = bid * EB;
    int end = min(base + EB, E);
    for (int i = base + tid; i < end; i += 256) atomicAdd(&h[dst[i] >> BKT_SH], 1);
    __syncthreads();
    segs[tid] = h[tid] ? atomicAdd(&bcur[tid], h[tid]) : 0;
    __syncthreads();
    for (int i = base + tid; i < end; i += 256) {
        int d = dst[i];
        int bk = d >> BKT_SH;
        int r = atomicAdd(&cur[bk], 1);
        ebuf[(size_t)bk * BCAP + segs[bk] + r] =
            (unsigned)src[i] | ((unsigned)(d & (BKT_SZ - 1)) << 17);
    }
}

// per-bucket counting sort -> compact ssorted + row_ptr + dinv; bucket counts come from bcur
__device__ __forceinline__ void dev_csr2(SmemU& sm, const unsigned* __restrict__ ebuf,
                                         const int* __restrict__ bcur, int n, int E,
                                         int* __restrict__ row_ptr, float* __restrict__ dinv,
                                         int* __restrict__ ssorted, int b) {
    int* cnt = sm.csr.cnt; int* exc = sm.csr.exc; int* cur2 = sm.csr.cur2; int* p = sm.csr.p;
    int tid = threadIdx.x;
    int v = bcur[tid];  // final bucket count (0 for unused buckets)
    p[tid] = v;
    __syncthreads();
    for (int o = 1; o < 256; o <<= 1) {
        int t = (tid >= o) ? p[tid - o] : 0;
        __syncthreads();
        p[tid] += t;
        __syncthreads();
    }
    int scnt = bcur[b];
    int s0 = p[b] - scnt;
    __syncthreads();
    if (b == 0 && tid == 0) row_ptr[n] = E;

    const unsigned* eb = &ebuf[(size_t)b * BCAP];
    int d0 = b << BKT_SH;
    int ndl = min(BKT_SZ, n - d0);
    cnt[tid] = 0; cur2[tid] = 0;
    __syncthreads();
    for (int i = tid; i < scnt; i += 256)
        atomicAdd(&cnt[(eb[i] >> 17) & (BKT_SZ - 1)], 1);
    __syncthreads();
    int c = cnt[tid];
    p[tid] = c;
    __syncthreads();
    for (int o = 1; o < 256; o <<= 1) {
        int t = (tid >= o) ? p[tid - o] : 0;
        __syncthreads();
        p[tid] += t;
        __syncthreads();
    }
    int exc_t = p[tid] - c;
    exc[tid] = exc_t;
    if (tid < ndl) {
        row_ptr[d0 + tid] = s0 + exc_t;
        dinv[d0 + tid] = rsqrtf((float)(c + 1));  // +1 self loop
    }
    __syncthreads();
    for (int i = tid; i < scnt; i += 256) {
        unsigned e = eb[i];
        int dl = (e >> 17) & (BKT_SZ - 1);
        int r = atomicAdd(&cur2[dl], 1);
        ssorted[s0 + exc[dl] + r] = (int)(e & 0x1FFFF);
    }
}

// GEMM1 body: h1_pre[64 rows of tile][64] = x[.,256] @ W[256,64] -> f16
__device__ __forceinline__ void dev_gemm1(SmemU& sm, const float* __restrict__ x,
                                          const float* __restrict__ W, f16* __restrict__ out,
                                          int n, int tile) {
    f16* WB = sm.g1.WB;
    f16* Ah = sm.g1.Ah;
    int tid = threadIdx.x;
    int row0 = tile * 64;

    for (int i = tid; i < 4096; i += 256) {
        int k = i >> 4, c4 = (i & 15) * 4;
        float4 w = *(const float4*)&W[k * 64 + c4];
        int t = c4 >> 4, ks = k >> 5, q = (k & 31) >> 3, j = k & 7;
        int base = (((t * 8 + ks) * 64 + q * 16 + (c4 & 15)) * 8) + j;
        WB[base + 0]  = (f16)w.x;
        WB[base + 8]  = (f16)w.y;
        WB[base + 16] = (f16)w.z;
        WB[base + 24] = (f16)w.w;
    }

    int lane = tid & 63, w = tid >> 6;
    int m = lane & 15, q = lane >> 4;

    f32x4 acc[4];
#pragma unroll
    for (int t = 0; t < 4; t++) acc[t] = (f32x4){0.f, 0.f, 0.f, 0.f};

    for (int h = 0; h < 2; h++) {
        __syncthreads();
        for (int i = tid; i < 2048; i += 256) {
            int r = i >> 5, k4 = (i & 31) * 4;
            float4 v = {0.f, 0.f, 0.f, 0.f};
            if (row0 + r < n) v = *(const float4*)&x[(size_t)(row0 + r) * 256 + 128 * h + k4];
            half4 hv;
            hv.x = (f16)v.x; hv.y = (f16)v.y; hv.z = (f16)v.z; hv.w = (f16)v.w;
            *(half4*)&Ah[r * 136 + k4] = hv;
        }
        __syncthreads();
#pragma unroll
        for (int ksl = 0; ksl < 4; ksl++) {
            int ks = 4 * h + ksl;
            f16x8 a = *(const f16x8*)&Ah[(16 * w + m) * 136 + 32 * ksl + 8 * q];
#pragma unroll
            for (int t = 0; t < 4; t++) {
                f16x8 b = *(const f16x8*)&WB[((t * 8 + ks) * 64 + lane) * 8];
                acc[t] = __builtin_amdgcn_mfma_f32_16x16x32_f16(a, b, acc[t], 0, 0, 0);
            }
        }
    }

#pragma unroll
    for (int t = 0; t < 4; t++) {
#pragma unroll
        for (int r = 0; r < 4; r++) {
            int gr = row0 + 16 * w + 4 * q + r;
            if (gr < n) out[(size_t)gr * 64 + 16 * t + m] = (f16)acc[t][r];
        }
    }
}

// ---------------- phase kernels: CSR stage (blocks [0,nA)) + gemm1 slice ---------

__global__ __launch_bounds__(256) void k_p1(const int* __restrict__ src, const int* __restrict__ dst,
                                            int E, int* __restrict__ bcur, unsigned* __restrict__ ebuf,
                                            const float* __restrict__ x, const float* __restrict__ W,
                                            f16* __restrict__ out, int n, int nA, int tile0) {
    __shared__ SmemU sm;
    if ((int)blockIdx.x < nA) dev_binA2(sm, src, dst, E, bcur, ebuf, blockIdx.x);
    else dev_gemm1(sm, x, W, out, n, tile0 + (int)blockIdx.x - nA);
}

__global__ __launch_bounds__(256) void k_p2(const unsigned* __restrict__ ebuf,
                                            const int* __restrict__ bcur, int n, int E,
                                            int* __restrict__ row_ptr, float* __restrict__ dinv,
                                            int* __restrict__ ssorted,
                                            const float* __restrict__ x, const float* __restrict__ W,
                                            f16* __restrict__ out, int nA, int tile0) {
    __shared__ SmemU sm;
    if ((int)blockIdx.x < nA) dev_csr2(sm, ebuf, bcur, n, E, row_ptr, dinv, ssorted, blockIdx.x);
    else dev_gemm1(sm, x, W, out, n, tile0 + (int)blockIdx.x - nA);
}

// ---------------- gather macro body (16-lane group, 8-deep unroll) ----------------
// Computes dd*(sum_s dinv[s]*h[s] + dd*h[d]) for features 4*fg..4*fg+3 of node d.

#define GCN_GATHER(hpre, d, fg, AX, AY, AZ, AW, DD)                                     \
    {                                                                                   \
        half4 hs_ = *(const half4*)&hpre[(size_t)(d) * 64 + 4 * (fg)];                  \
        AX = DD * (float)hs_.x; AY = DD * (float)hs_.y;                                 \
        AZ = DD * (float)hs_.z; AW = DD * (float)hs_.w;                                 \
        int s0_ = row_ptr[d], s1_ = row_ptr[(d) + 1];                                   \
        for (int base_ = s0_; base_ < s1_; base_ += 16) {                               \
            int j_ = base_ + (fg);                                                      \
            int slv_ = 0;                                                               \
            float wl_ = 0.f;                                                            \
            if (j_ < s1_) { slv_ = ssorted[j_]; wl_ = dinv[slv_]; }                     \
            int cnt_ = min(16, s1_ - base_);                                            \
            for (int i_ = 0; i_ < cnt_; i_ += 8) {                                      \
                int a0 = __shfl(slv_, i_ + 0, 16), a1 = __shfl(slv_, i_ + 1, 16);       \
                int a2 = __shfl(slv_, i_ + 2, 16), a3 = __shfl(slv_, i_ + 3, 16);       \
                int a4 = __shfl(slv_, i_ + 4, 16), a5 = __shfl(slv_, i_ + 5, 16);       \
                int a6 = __shfl(slv_, i_ + 6, 16), a7 = __shfl(slv_, i_ + 7, 16);       \
                float w0 = __shfl(wl_, i_ + 0, 16), w1 = __shfl(wl_, i_ + 1, 16);       \
                float w2 = __shfl(wl_, i_ + 2, 16), w3 = __shfl(wl_, i_ + 3, 16);       \
                float w4 = __shfl(wl_, i_ + 4, 16), w5 = __shfl(wl_, i_ + 5, 16);       \
                float w6 = __shfl(wl_, i_ + 6, 16), w7 = __shfl(wl_, i_ + 7, 16);       \
                half4 h0 = *(const half4*)&hpre[(size_t)a0 * 64 + 4 * (fg)];            \
                half4 h1 = *(const half4*)&hpre[(size_t)a1 * 64 + 4 * (fg)];            \
                half4 h2 = *(const half4*)&hpre[(size_t)a2 * 64 + 4 * (fg)];            \
                half4 h3 = *(const half4*)&hpre[(size_t)a3 * 64 + 4 * (fg)];            \
                half4 h4 = *(const half4*)&hpre[(size_t)a4 * 64 + 4 * (fg)];            \
                half4 h5 = *(const half4*)&hpre[(size_t)a5 * 64 + 4 * (fg)];            \
                half4 h6 = *(const half4*)&hpre[(size_t)a6 * 64 + 4 * (fg)];            \
                half4 h7 = *(const half4*)&hpre[(size_t)a7 * 64 + 4 * (fg)];            \
                AX += w0 * (float)h0.x; AY += w0 * (float)h0.y;                         \
                AZ += w0 * (float)h0.z; AW += w0 * (float)h0.w;                         \
                AX += w1 * (float)h1.x; AY += w1 * (float)h1.y;                         \
                AZ += w1 * (float)h1.z; AW += w1 * (float)h1.w;                         \
                AX += w2 * (float)h2.x; AY += w2 * (float)h2.y;                         \
                AZ += w2 * (float)h2.z; AW += w2 * (float)h2.w;                         \
                AX += w3 * (float)h3.x; AY += w3 * (float)h3.y;                         \
                AZ += w3 * (float)h3.z; AW += w3 * (float)h3.w;                         \
                AX += w4 * (float)h4.x; AY += w4 * (float)h4.y;                         \
                AZ += w4 * (float)h4.z; AW += w4 * (float)h4.w;                         \
                AX += w5 * (float)h5.x; AY += w5 * (float)h5.y;                         \
                AZ += w5 * (float)h5.z; AW += w5 * (float)h5.w;                         \
                AX += w6 * (float)h6.x; AY += w6 * (float)h6.y;                         \
                AZ += w6 * (float)h6.z; AW += w6 * (float)h6.w;                         \
                AX += w7 * (float)h7.x; AY += w7 * (float)h7.y;                         \
                AZ += w7 * (float)h7.z; AW += w7 * (float)h7.w;                         \
            }                                                                           \
        }                                                                               \
    }

// ---------------- fused prop1 + middle (MFMA): 64 nodes per block ----------------

__global__ __launch_bounds__(256, 4) void k_midf(const f16* __restrict__ h1pre,
                                                 const int* __restrict__ row_ptr,
                                                 const int* __restrict__ ssorted,
                                                 const float* __restrict__ dinv,
                                                 const float* __restrict__ benc,
                                                 const float* __restrict__ Wz, const float* __restrict__ bz,
                                                 const float* __restrict__ Wd, const float* __restrict__ bd,
                                                 const float* __restrict__ Wc, const float* __restrict__ bc,
                                                 f16* __restrict__ hd_ws,
                                                 float* __restrict__ z_out, float* __restrict__ pred_out,
                                                 int n) {
    __shared__ __attribute__((aligned(16))) f16 Ah[64 * 72];
    __shared__ __attribute__((aligned(16))) f16 Zh[64 * 40];
    __shared__ __attribute__((aligned(16))) f16 WzB[2 * 2 * 64 * 8];
    __shared__ __attribute__((aligned(16))) f16 WdB[4 * 64 * 8];
    __shared__ float Wcs[32 * 4];
    __shared__ float bzs[32], bds[64], bcs[4], bes[64];
    int tid = threadIdx.x;
    int row0 = blockIdx.x * 64;

    for (int i = tid; i < 2048; i += 256) {
        int k = i >> 5, c = i & 31;
        int ks = k >> 5, q = (k >> 3) & 3, j = k & 7;
        int t = c >> 4, ln = q * 16 + (c & 15);
        WzB[((t * 2 + ks) * 64 + ln) * 8 + j] = (f16)Wz[i];
    }
    for (int i = tid; i < 2048; i += 256) {
        int k = i >> 6, c = i & 63;
        int q = k >> 3, j = k & 7;
        int t = c >> 4, ln = q * 16 + (c & 15);
        WdB[(t * 64 + ln) * 8 + j] = (f16)Wd[i];
    }
    if (tid < 96) Wcs[(tid / 3) * 4 + (tid % 3)] = Wc[tid];
    if (tid < 32) bzs[tid] = bz[tid];
    if (tid < 64) bds[tid] = bd[tid];
    if (tid < 3)  bcs[tid] = bc[tid];
    if (tid < 64) bes[tid] = benc[tid];
    __syncthreads();  // bes ready before gather

    int lane = tid & 63, wid = tid >> 6;
    int g = lane >> 4, fg = lane & 15;

    // gather phase: each wave fills its 16 rows of Ah in 4 rounds of 4 parallel nodes
    for (int r = 0; r < 4; r++) {
        int no = 16 * wid + 4 * r + g;
        int d = row0 + no;
        float vx = 0.f, vy = 0.f, vz = 0.f, vw = 0.f;
        if (d < n) {
            float dd = dinv[d];
            float ax, ay, az, aw;
            GCN_GATHER(h1pre, d, fg, ax, ay, az, aw, dd);
            float4 b = *(float4*)&bes[4 * fg];
            vx = fmaxf(dd * ax + b.x, 0.f); vy = fmaxf(dd * ay + b.y, 0.f);
            vz = fmaxf(dd * az + b.z, 0.f); vw = fmaxf(dd * aw + b.w, 0.f);
        }
        half4 hv;
        hv.x = (f16)vx; hv.y = (f16)vy; hv.z = (f16)vz; hv.w = (f16)vw;
        *(half4*)&Ah[no * 72 + 4 * fg] = hv;
    }
    __syncthreads();

    int m = lane & 15, q = lane >> 4;

    f32x4 za[2];
    za[0] = (f32x4){0.f, 0.f, 0.f, 0.f};
    za[1] = (f32x4){0.f, 0.f, 0.f, 0.f};
#pragma unroll
    for (int ks = 0; ks < 2; ks++) {
        f16x8 a = *(const f16x8*)&Ah[(16 * wid + m) * 72 + 32 * ks + 8 * q];
#pragma unroll
        for (int t = 0; t < 2; t++) {
            f16x8 b = *(const f16x8*)&WzB[((t * 2 + ks) * 64 + lane) * 8];
            za[t] = __builtin_amdgcn_mfma_f32_16x16x32_f16(a, b, za[t], 0, 0, 0);
        }
    }
#pragma unroll
    for (int t = 0; t < 2; t++) {
        float bj = bzs[16 * t + m];
#pragma unroll
        for (int r = 0; r < 4; r++) {
            int node = 16 * wid + 4 * q + r;
            float zv = za[t][r] + bj;
            Zh[node * 40 + 16 * t + m] = (f16)zv;
            if (row0 + node < n) z_out[(size_t)(row0 + node) * 32 + 16 * t + m] = zv;
        }
    }
    __syncthreads();

    f16x8 a2 = *(const f16x8*)&Zh[(16 * wid + m) * 40 + 8 * q];
    f32x4 hb[4];
#pragma unroll
    for (int t = 0; t < 4; t++) {
        f16x8 b = *(const f16x8*)&WdB[(t * 64 + lane) * 8];
        f32x4 zero = (f32x4){0.f, 0.f, 0.f, 0.f};
        hb[t] = __builtin_amdgcn_mfma_f32_16x16x32_f16(a2, b, zero, 0, 0, 0);
    }
#pragma unroll
    for (int t = 0; t < 4; t++) {
        float bf = bds[16 * t + m];
#pragma unroll
        for (int r = 0; r < 4; r++) {
            int node = 16 * wid + 4 * q + r;
            if (row0 + node < n)
                hd_ws[(size_t)(row0 + node) * 64 + 16 * t + m] = (f16)fmaxf(hb[t][r] + bf, 0.f);
        }
    }

    if (tid < 64) {
        int node = tid;
        float pa = bcs[0], pb = bcs[1], pc = bcs[2];
        for (int k = 0; k < 32; k++) {
            float zv = (float)Zh[node * 40 + k];
            pa += zv * Wcs[k * 4 + 0];
            pb += zv * Wcs[k * 4 + 1];
            pc += zv * Wcs[k * 4 + 2];
        }
        if (row0 + node < n) {
            pred_out[(size_t)(row0 + node) * 3 + 0] = pa;
            pred_out[(size_t)(row0 + node) * 3 + 1] = pb;
            pred_out[(size_t)(row0 + node) * 3 + 2] = pc;
        }
    }
}

// ---------------- fused prop2 + GEMM5: x_recon = (P hd)[64 rows] @ W_dec + b ----------
// W_dec staged in two 16 KB halves to keep LDS ~26 KB (6 blocks/CU).

__global__ __launch_bounds__(256, 4) void k_decf(const f16* __restrict__ hd,
                                                 const int* __restrict__ row_ptr,
                                                 const int* __restrict__ ssorted,
                                                 const float* __restrict__ dinv,
                                                 const float* __restrict__ W,
                                                 const float* __restrict__ bias,
                                                 float* __restrict__ out, int n) {
    __shared__ __attribute__((aligned(16))) f16 WBh[8 * 2 * 64 * 8];  // 16 KB (8 t-values)
    __shared__ __attribute__((aligned(16))) f16 Ah[64 * 72];          // 9 KB
    __shared__ float bs[256];
    int tid = threadIdx.x;
    int row0 = blockIdx.x * 64;

    bs[tid] = bias[tid];

    int lane = tid & 63, wid = tid >> 6;
    int g = lane >> 4, fg = lane & 15;

    // gather phase: P(hd) rows -> Ah
    for (int r = 0; r < 4; r++) {
        int no = 16 * wid + 4 * r + g;
        int d = row0 + no;
        float vx = 0.f, vy = 0.f, vz = 0.f, vw = 0.f;
        if (d < n) {
            float dd = dinv[d];
            float ax, ay, az, aw;
            GCN_GATHER(hd, d, fg, ax, ay, az, aw, dd);
            vx = dd * ax; vy = dd * ay; vz = dd * az; vw = dd * aw;
        }
        half4 hv;
        hv.x = (f16)vx; hv.y = (f16)vy; hv.z = (f16)vz; hv.w = (f16)vw;
        *(half4*)&Ah[no * 72 + 4 * fg] = hv;
    }
    __syncthreads();

    int m = lane & 15, q = lane >> 4;

    f16x8 a0 = *(const f16x8*)&Ah[(16 * wid + m) * 72 + 0 + 8 * q];
    f16x8 a1 = *(const f16x8*)&Ah[(16 * wid + m) * 72 + 32 + 8 * q];

    int gr0 = row0 + 16 * wid + 4 * q;
    bool full = (gr0 + 3 < n);

    for (int hf = 0; hf < 2; hf++) {
        __syncthreads();  // protect WBh reuse across halves
        for (int i = tid; i < 2048; i += 256) {
            int k = i >> 5;
            int c4 = (i & 31) * 4 + 128 * hf;
            float4 w4 = *(const float4*)&W[k * 256 + c4];
            int ks = k >> 5, q2 = (k >> 3) & 3, j = k & 7;
            int tl = (c4 >> 4) - 8 * hf;  // 0..7
            int basei = ((tl * 2 + ks) * 64 + q2 * 16 + (c4 & 15)) * 8 + j;
            WBh[basei + 0]  = (f16)w4.x;
            WBh[basei + 8]  = (f16)w4.y;
            WBh[basei + 16] = (f16)w4.z;
            WBh[basei + 24] = (f16)w4.w;
        }
        __syncthreads();
#pragma unroll
        for (int tl = 0; tl < 8; tl++) {
            int t = 8 * hf + tl;
            f32x4 acc = (f32x4){0.f, 0.f, 0.f, 0.f};
            f16x8 b0 = *(const f16x8*)&WBh[((tl * 2 + 0) * 64 + lane) * 8];
            acc = __builtin_amdgcn_mfma_f32_16x16x32_f16(a0, b0, acc, 0, 0, 0);
            f16x8 b1 = *(const f16x8*)&WBh[((tl * 2 + 1) * 64 + lane) * 8];
            acc = __builtin_amdgcn_mfma_f32_16x16x32_f16(a1, b1, acc, 0, 0, 0);
            float bf = bs[16 * t + m];
            if (full) {
#pragma unroll
                for (int r = 0; r < 4; r++)
                    out[(size_t)(gr0 + r) * 256 + 16 * t + m] = acc[r] + bf;
            } else {
#pragma unroll
                for (int r = 0; r < 4; r++)
                    if (gr0 + r < n) out[(size_t)(gr0 + r) * 256 + 16 * t + m] = acc[r] + bf;
            }
        }
    }
}

// ---------------- launch ----------------

extern "C" void kernel_launch(void* const* d_in, const int* in_sizes, int n_in,
                              void* d_out, int out_size, void* d_ws, size_t ws_size,
                              hipStream_t stream) {
    const float* x    = (const float*)d_in[0];
    const int*   ei   = (const int*)d_in[1];
    const float* Wenc = (const float*)d_in[3];
    const float* benc = (const float*)d_in[4];
    const float* Wz   = (const float*)d_in[5];
    const float* bz   = (const float*)d_in[6];
    const float* Wd   = (const float*)d_in[7];
    const float* bd   = (const float*)d_in[8];
    const float* Wdec = (const float*)d_in[9];
    const float* bdec = (const float*)d_in[10];
    const float* Wc   = (const float*)d_in[11];
    const float* bc   = (const float*)d_in[12];

    int n = in_sizes[0] / 256;
    int E = in_sizes[1] / 2;
    const int* src = ei;
    const int* dst = ei + E;

    int nbk = (n + BKT_SZ - 1) >> BKT_SH;
    int nbin = (E + EB - 1) / EB;

    char* w = (char*)d_ws;
    size_t off = 0;
    auto alloc = [&](size_t bytes) {
        void* p = w + off;
        off = (off + bytes + 255) & ~(size_t)255;
        return p;
    };
    int*      row_ptr = (int*)alloc(sizeof(int) * (n + 1));
    int*      ssorted = (int*)alloc(sizeof(int) * E);
    unsigned* ebuf    = (unsigned*)alloc(sizeof(unsigned) * (size_t)nbk * BCAP);
    float*    dinv    = (float*)alloc(sizeof(float) * n);
    int*      bcur    = (int*)alloc(sizeof(int) * 256);
    f16*      bufA    = (f16*)alloc(sizeof(f16) * (size_t)n * 64);  // h1pre
    f16*      bufB    = (f16*)alloc(sizeof(f16) * (size_t)n * 64);  // hd
    (void)ws_size; (void)n_in; (void)out_size;

    float* out_xr = (float*)d_out;
    float* out_z  = out_xr + (size_t)n * 256;
    float* out_p  = out_z + (size_t)n * 32;

    int tiles = (n + 63) / 64;
    int th = tiles / 2;

    hipMemsetAsync(bcur, 0, sizeof(int) * 256, stream);

    // phase 1: binning || gemm1 tiles [0, th)
    k_p1<<<dim3(nbin + th), dim3(256), 0, stream>>>(src, dst, E, bcur, ebuf,
                                                    x, Wenc, bufA, n, nbin, 0);
    // phase 2: per-bucket CSR || gemm1 tiles [th, tiles)
    k_p2<<<dim3(nbk + (tiles - th)), dim3(256), 0, stream>>>(ebuf, bcur, n, E, row_ptr, dinv, ssorted,
                                                             x, Wenc, bufA, nbk, th);

    // fused prop1 + middle: z (out), pred (out), hd -> bufB
    k_midf<<<dim3(tiles), dim3(256), 0, stream>>>(bufA, row_ptr, ssorted, dinv, benc,
                                                  Wz, bz, Wd, bd, Wc, bc,
                                                  bufB, out_z, out_p, n);

    // fused prop2 + decoder GEMM: x_recon = P(bufB) @ W_dec + b_dec
    k_decf<<<dim3(tiles), dim3(256), 0, stream>>>(bufB, row_ptr, ssorted, dinv,
                                                  Wdec, bdec, out_xr, n);
}

// Round 10
// 212.876 us; speedup vs baseline: 3.4215x; 1.0656x over previous
//
#include <hip/hip_runtime.h>
#include <stdint.h>

typedef _Float16 f16;
typedef _Float16 half4 __attribute__((ext_vector_type(4)));
typedef _Float16 f16x8 __attribute__((ext_vector_type(8)));
typedef float f32x4 __attribute__((ext_vector_type(4)));

// ---------------- CSR build params: 256-node buckets, bucket-strided ebuf ----------------

#define BKT_SH 8
#define BKT_SZ 256
#define EB 4096
#define BCAP 16384  // per-bucket capacity (uniform-random E=800k over 196 buckets -> max ~4.4k)

struct __attribute__((aligned(16))) G1S { f16 WB[4 * 8 * 64 * 8]; f16 Ah[64 * 136]; };  // 49 KB
struct BinS { int h[256], segs[256], cur[256]; };
struct CsrS { int cnt[256], exc[256], cur2[256], p[256]; };
union __attribute__((aligned(16))) SmemU { G1S g1; BinS bin; CsrS csr; };

// ---------------- CSR device bodies (256 threads) ----------------

__device__ __forceinline__ void dev_binA2(SmemU& sm, const int* __restrict__ src,
                                          const int* __restrict__ dst, int E,
                                          int* __restrict__ bcur, unsigned* __restrict__ ebuf,
                                          int bid) {
    int* h = sm.bin.h; int* segs = sm.bin.segs; int* cur = sm.bin.cur;
    int tid = threadIdx.x;
    h[tid] = 0; cur[tid] = 0;
    __syncthreads();
    int base = bid * EB;
    int end = min(base + EB, E);
    for (int i = base + tid; i < end; i += 256) atomicAdd(&h[dst[i] >> BKT_SH], 1);
    __syncthreads();
    segs[tid] = h[tid] ? atomicAdd(&bcur[tid], h[tid]) : 0;
    __syncthreads();
    for (int i = base + tid; i < end; i += 256) {
        int d = dst[i];
        int bk = d >> BKT_SH;
        int r = atomicAdd(&cur[bk], 1);
        ebuf[(size_t)bk * BCAP + segs[bk] + r] =
            (unsigned)src[i] | ((unsigned)(d & (BKT_SZ - 1)) << 17);
    }
}

__device__ __forceinline__ void dev_csr2(SmemU& sm, const unsigned* __restrict__ ebuf,
                                         const int* __restrict__ bcur, int n, int E,
                                         int* __restrict__ row_ptr, float* __restrict__ dinv,
                                         int* __restrict__ ssorted, int b) {
    int* cnt = sm.csr.cnt; int* exc = sm.csr.exc; int* cur2 = sm.csr.cur2; int* p = sm.csr.p;
    int tid = threadIdx.x;
    int v = bcur[tid];
    p[tid] = v;
    __syncthreads();
    for (int o = 1; o < 256; o <<= 1) {
        int t = (tid >= o) ? p[tid - o] : 0;
        __syncthreads();
        p[tid] += t;
        __syncthreads();
    }
    int scnt = bcur[b];
    int s0 = p[b] - scnt;
    __syncthreads();
    if (b == 0 && tid == 0) row_ptr[n] = E;

    const unsigned* eb = &ebuf[(size_t)b * BCAP];
    int d0 = b << BKT_SH;
    int ndl = min(BKT_SZ, n - d0);
    cnt[tid] = 0; cur2[tid] = 0;
    __syncthreads();
    for (int i = tid; i < scnt; i += 256)
        atomicAdd(&cnt[(eb[i] >> 17) & (BKT_SZ - 1)], 1);
    __syncthreads();
    int c = cnt[tid];
    p[tid] = c;
    __syncthreads();
    for (int o = 1; o < 256; o <<= 1) {
        int t = (tid >= o) ? p[tid - o] : 0;
        __syncthreads();
        p[tid] += t;
        __syncthreads();
    }
    int exc_t = p[tid] - c;
    exc[tid] = exc_t;
    if (tid < ndl) {
        row_ptr[d0 + tid] = s0 + exc_t;
        dinv[d0 + tid] = rsqrtf((float)(c + 1));  // +1 self loop
    }
    __syncthreads();
    for (int i = tid; i < scnt; i += 256) {
        unsigned e = eb[i];
        int dl = (e >> 17) & (BKT_SZ - 1);
        int r = atomicAdd(&cur2[dl], 1);
        ssorted[s0 + exc[dl] + r] = (int)(e & 0x1FFFF);
    }
}

// GEMM1 body: h1_pre[64 rows of tile][64] = x[.,256] @ W[256,64] -> f16
// W staging: one f16x8 octet per thread-iter (8 strided reads, 1 dense 16B LDS write).
__device__ __forceinline__ void dev_gemm1(SmemU& sm, const float* __restrict__ x,
                                          const float* __restrict__ W, f16* __restrict__ out,
                                          int n, int tile) {
    f16* WB = sm.g1.WB;
    f16* Ah = sm.g1.Ah;
    int tid = threadIdx.x;
    int row0 = tile * 64;

    for (int i = tid; i < 2048; i += 256) {  // 2048 octets
        int m = i & 15, q = (i >> 4) & 3, ks = (i >> 6) & 7, t = i >> 9;
        int col = 16 * t + m;
        int k0 = ks * 32 + q * 8;
        f16x8 v;
#pragma unroll
        for (int j = 0; j < 8; j++) v[j] = (f16)W[(k0 + j) * 64 + col];
        *(f16x8*)&WB[i * 8] = v;
    }

    int lane = tid & 63, w = tid >> 6;
    int m = lane & 15, q = lane >> 4;

    f32x4 acc[4];
#pragma unroll
    for (int t = 0; t < 4; t++) acc[t] = (f32x4){0.f, 0.f, 0.f, 0.f};

    for (int h = 0; h < 2; h++) {
        __syncthreads();
        for (int i = tid; i < 2048; i += 256) {
            int r = i >> 5, k4 = (i & 31) * 4;
            float4 v = {0.f, 0.f, 0.f, 0.f};
            if (row0 + r < n) v = *(const float4*)&x[(size_t)(row0 + r) * 256 + 128 * h + k4];
            half4 hv;
            hv.x = (f16)v.x; hv.y = (f16)v.y; hv.z = (f16)v.z; hv.w = (f16)v.w;
            *(half4*)&Ah[r * 136 + k4] = hv;
        }
        __syncthreads();
#pragma unroll
        for (int ksl = 0; ksl < 4; ksl++) {
            int ks = 4 * h + ksl;
            f16x8 a = *(const f16x8*)&Ah[(16 * w + m) * 136 + 32 * ksl + 8 * q];
#pragma unroll
            for (int t = 0; t < 4; t++) {
                f16x8 b = *(const f16x8*)&WB[((t * 8 + ks) * 64 + lane) * 8];
                acc[t] = __builtin_amdgcn_mfma_f32_16x16x32_f16(a, b, acc[t], 0, 0, 0);
            }
        }
    }

#pragma unroll
    for (int t = 0; t < 4; t++) {
#pragma unroll
        for (int r = 0; r < 4; r++) {
            int gr = row0 + 16 * w + 4 * q + r;
            if (gr < n) out[(size_t)gr * 64 + 16 * t + m] = (f16)acc[t][r];
        }
    }
}

// ---------------- phase kernels: CSR stage (blocks [0,nA)) + gemm1 slice ---------

__global__ __launch_bounds__(256) void k_p1(const int* __restrict__ src, const int* __restrict__ dst,
                                            int E, int* __restrict__ bcur, unsigned* __restrict__ ebuf,
                                            const float* __restrict__ x, const float* __restrict__ W,
                                            f16* __restrict__ out, int n, int nA, int tile0) {
    __shared__ SmemU sm;
    if ((int)blockIdx.x < nA) dev_binA2(sm, src, dst, E, bcur, ebuf, blockIdx.x);
    else dev_gemm1(sm, x, W, out, n, tile0 + (int)blockIdx.x - nA);
}

__global__ __launch_bounds__(256) void k_p2(const unsigned* __restrict__ ebuf,
                                            const int* __restrict__ bcur, int n, int E,
                                            int* __restrict__ row_ptr, float* __restrict__ dinv,
                                            int* __restrict__ ssorted,
                                            const float* __restrict__ x, const float* __restrict__ W,
                                            f16* __restrict__ out, int nA, int tile0) {
    __shared__ SmemU sm;
    if ((int)blockIdx.x < nA) dev_csr2(sm, ebuf, bcur, n, E, row_ptr, dinv, ssorted, blockIdx.x);
    else dev_gemm1(sm, x, W, out, n, tile0 + (int)blockIdx.x - nA);
}

// ---------------- gather macro body (16-lane group, 8-deep unroll) ----------------

#define GCN_GATHER(hpre, d, fg, AX, AY, AZ, AW, DD)                                     \
    {                                                                                   \
        half4 hs_ = *(const half4*)&hpre[(size_t)(d) * 64 + 4 * (fg)];                  \
        AX = DD * (float)hs_.x; AY = DD * (float)hs_.y;                                 \
        AZ = DD * (float)hs_.z; AW = DD * (float)hs_.w;                                 \
        int s0_ = row_ptr[d], s1_ = row_ptr[(d) + 1];                                   \
        for (int base_ = s0_; base_ < s1_; base_ += 16) {                               \
            int j_ = base_ + (fg);                                                      \
            int slv_ = 0;                                                               \
            float wl_ = 0.f;                                                            \
            if (j_ < s1_) { slv_ = ssorted[j_]; wl_ = dinv[slv_]; }                     \
            int cnt_ = min(16, s1_ - base_);                                            \
            for (int i_ = 0; i_ < cnt_; i_ += 8) {                                      \
                int a0 = __shfl(slv_, i_ + 0, 16), a1 = __shfl(slv_, i_ + 1, 16);       \
                int a2 = __shfl(slv_, i_ + 2, 16), a3 = __shfl(slv_, i_ + 3, 16);       \
                int a4 = __shfl(slv_, i_ + 4, 16), a5 = __shfl(slv_, i_ + 5, 16);       \
                int a6 = __shfl(slv_, i_ + 6, 16), a7 = __shfl(slv_, i_ + 7, 16);       \
                float w0 = __shfl(wl_, i_ + 0, 16), w1 = __shfl(wl_, i_ + 1, 16);       \
                float w2 = __shfl(wl_, i_ + 2, 16), w3 = __shfl(wl_, i_ + 3, 16);       \
                float w4 = __shfl(wl_, i_ + 4, 16), w5 = __shfl(wl_, i_ + 5, 16);       \
                float w6 = __shfl(wl_, i_ + 6, 16), w7 = __shfl(wl_, i_ + 7, 16);       \
                half4 h0 = *(const half4*)&hpre[(size_t)a0 * 64 + 4 * (fg)];            \
                half4 h1 = *(const half4*)&hpre[(size_t)a1 * 64 + 4 * (fg)];            \
                half4 h2 = *(const half4*)&hpre[(size_t)a2 * 64 + 4 * (fg)];            \
                half4 h3 = *(const half4*)&hpre[(size_t)a3 * 64 + 4 * (fg)];            \
                half4 h4 = *(const half4*)&hpre[(size_t)a4 * 64 + 4 * (fg)];            \
                half4 h5 = *(const half4*)&hpre[(size_t)a5 * 64 + 4 * (fg)];            \
                half4 h6 = *(const half4*)&hpre[(size_t)a6 * 64 + 4 * (fg)];            \
                half4 h7 = *(const half4*)&hpre[(size_t)a7 * 64 + 4 * (fg)];            \
                AX += w0 * (float)h0.x; AY += w0 * (float)h0.y;                         \
                AZ += w0 * (float)h0.z; AW += w0 * (float)h0.w;                         \
                AX += w1 * (float)h1.x; AY += w1 * (float)h1.y;                         \
                AZ += w1 * (float)h1.z; AW += w1 * (float)h1.w;                         \
                AX += w2 * (float)h2.x; AY += w2 * (float)h2.y;                         \
                AZ += w2 * (float)h2.z; AW += w2 * (float)h2.w;                         \
                AX += w3 * (float)h3.x; AY += w3 * (float)h3.y;                         \
                AZ += w3 * (float)h3.z; AW += w3 * (float)h3.w;                         \
                AX += w4 * (float)h4.x; AY += w4 * (float)h4.y;                         \
                AZ += w4 * (float)h4.z; AW += w4 * (float)h4.w;                         \
                AX += w5 * (float)h5.x; AY += w5 * (float)h5.y;                         \
                AZ += w5 * (float)h5.z; AW += w5 * (float)h5.w;                         \
                AX += w6 * (float)h6.x; AY += w6 * (float)h6.y;                         \
                AZ += w6 * (float)h6.z; AW += w6 * (float)h6.w;                         \
                AX += w7 * (float)h7.x; AY += w7 * (float)h7.y;                         \
                AZ += w7 * (float)h7.z; AW += w7 * (float)h7.w;                         \
            }                                                                           \
        }                                                                               \
    }

// ---------------- fused prop1 + middle (MFMA): 64 nodes per block, 8 waves ----------------
// Waves: rowg = wid&3 (16-row group), tsel = wid>>2 (output-column half).

__global__ __launch_bounds__(512, 6) void k_midf(const f16* __restrict__ h1pre,
                                                 const int* __restrict__ row_ptr,
                                                 const int* __restrict__ ssorted,
                                                 const float* __restrict__ dinv,
                                                 const float* __restrict__ benc,
                                                 const float* __restrict__ Wz, const float* __restrict__ bz,
                                                 const float* __restrict__ Wd, const float* __restrict__ bd,
                                                 const float* __restrict__ Wc, const float* __restrict__ bc,
                                                 f16* __restrict__ hd_ws,
                                                 float* __restrict__ z_out, float* __restrict__ pred_out,
                                                 int n) {
    __shared__ __attribute__((aligned(16))) f16 Ah[64 * 72];
    __shared__ __attribute__((aligned(16))) f16 Zh[64 * 40];
    __shared__ __attribute__((aligned(16))) f16 WzB[2 * 2 * 64 * 8];
    __shared__ __attribute__((aligned(16))) f16 WdB[4 * 64 * 8];
    __shared__ float Wcs[32 * 4];
    __shared__ float bzs[32], bds[64], bcs[4], bes[64];
    int tid = threadIdx.x;
    int row0 = blockIdx.x * 64;

    // WzB: 256 octets, conflict-free
    if (tid < 256) {
        int i = tid;
        int m = i & 15, q = (i >> 4) & 3, ks = (i >> 6) & 1, t = i >> 7;
        int col = 16 * t + m;
        int k0 = ks * 32 + q * 8;
        f16x8 v;
#pragma unroll
        for (int j = 0; j < 8; j++) v[j] = (f16)Wz[(k0 + j) * 32 + col];
        *(f16x8*)&WzB[i * 8] = v;
    } else {
        // WdB: 256 octets, conflict-free
        int i = tid - 256;
        int m = i & 15, q = (i >> 4) & 3, t = i >> 6;
        int col = 16 * t + m;
        int k0 = q * 8;
        f16x8 v;
#pragma unroll
        for (int j = 0; j < 8; j++) v[j] = (f16)Wd[(k0 + j) * 64 + col];
        *(f16x8*)&WdB[i * 8] = v;
    }
    if (tid < 96) Wcs[(tid / 3) * 4 + (tid % 3)] = Wc[tid];
    if (tid < 32) bzs[tid] = bz[tid];
    if (tid < 64) bds[tid] = bd[tid];
    if (tid < 3)  bcs[tid] = bc[tid];
    if (tid < 64) bes[tid] = benc[tid];
    __syncthreads();  // bes ready before gather

    int lane = tid & 63, wid = tid >> 6;  // wid 0..7
    int g = lane >> 4, fg = lane & 15;

    // gather phase: 32 node-slots per round, 2 rounds
    for (int r = 0; r < 2; r++) {
        int no = 32 * r + 4 * wid + g;
        int d = row0 + no;
        float vx = 0.f, vy = 0.f, vz = 0.f, vw = 0.f;
        if (d < n) {
            float dd = dinv[d];
            float ax, ay, az, aw;
            GCN_GATHER(h1pre, d, fg, ax, ay, az, aw, dd);
            float4 b = *(float4*)&bes[4 * fg];
            vx = fmaxf(dd * ax + b.x, 0.f); vy = fmaxf(dd * ay + b.y, 0.f);
            vz = fmaxf(dd * az + b.z, 0.f); vw = fmaxf(dd * aw + b.w, 0.f);
        }
        half4 hv;
        hv.x = (f16)vx; hv.y = (f16)vy; hv.z = (f16)vz; hv.w = (f16)vw;
        *(half4*)&Ah[no * 72 + 4 * fg] = hv;
    }
    __syncthreads();

    int m = lane & 15, q = lane >> 4;
    int rowg = wid & 3, tsel = wid >> 2;

    // z = Ah @ Wz + bz : wave handles t = tsel
    f32x4 za = (f32x4){0.f, 0.f, 0.f, 0.f};
#pragma unroll
    for (int ks = 0; ks < 2; ks++) {
        f16x8 a = *(const f16x8*)&Ah[(16 * rowg + m) * 72 + 32 * ks + 8 * q];
        f16x8 b = *(const f16x8*)&WzB[((tsel * 2 + ks) * 64 + lane) * 8];
        za = __builtin_amdgcn_mfma_f32_16x16x32_f16(a, b, za, 0, 0, 0);
    }
    {
        float bj = bzs[16 * tsel + m];
#pragma unroll
        for (int r = 0; r < 4; r++) {
            int node = 16 * rowg + 4 * q + r;
            float zv = za[r] + bj;
            Zh[node * 40 + 16 * tsel + m] = (f16)zv;
            if (row0 + node < n) z_out[(size_t)(row0 + node) * 32 + 16 * tsel + m] = zv;
        }
    }
    __syncthreads();

    // hd = relu(Zh @ Wd + bd) : wave handles t = 2*tsel + {0,1}
    f16x8 a2 = *(const f16x8*)&Zh[(16 * rowg + m) * 40 + 8 * q];
#pragma unroll
    for (int tt = 0; tt < 2; tt++) {
        int t = 2 * tsel + tt;
        f32x4 zero = (f32x4){0.f, 0.f, 0.f, 0.f};
        f16x8 b = *(const f16x8*)&WdB[(t * 64 + lane) * 8];
        f32x4 hb = __builtin_amdgcn_mfma_f32_16x16x32_f16(a2, b, zero, 0, 0, 0);
        float bf = bds[16 * t + m];
#pragma unroll
        for (int r = 0; r < 4; r++) {
            int node = 16 * rowg + 4 * q + r;
            if (row0 + node < n)
                hd_ws[(size_t)(row0 + node) * 64 + 16 * t + m] = (f16)fmaxf(hb[r] + bf, 0.f);
        }
    }

    if (tid < 64) {
        int node = tid;
        float pa = bcs[0], pb = bcs[1], pc = bcs[2];
        for (int k = 0; k < 32; k++) {
            float zv = (float)Zh[node * 40 + k];
            pa += zv * Wcs[k * 4 + 0];
            pb += zv * Wcs[k * 4 + 1];
            pc += zv * Wcs[k * 4 + 2];
        }
        if (row0 + node < n) {
            pred_out[(size_t)(row0 + node) * 3 + 0] = pa;
            pred_out[(size_t)(row0 + node) * 3 + 1] = pb;
            pred_out[(size_t)(row0 + node) * 3 + 2] = pc;
        }
    }
}

// ---------------- fused prop2 + GEMM5: 64 nodes per block, 8 waves, full-W staged ------
// Waves: rowg = wid&3 (16-row group), th = wid>>2 (t-half: t = 8*th + tl).

__global__ __launch_bounds__(512, 6) void k_decf(const f16* __restrict__ hd,
                                                 const int* __restrict__ row_ptr,
                                                 const int* __restrict__ ssorted,
                                                 const float* __restrict__ dinv,
                                                 const float* __restrict__ W,
                                                 const float* __restrict__ bias,
                                                 float* __restrict__ out, int n) {
    __shared__ __attribute__((aligned(16))) f16 WB[16 * 2 * 64 * 8];  // 32 KB
    __shared__ __attribute__((aligned(16))) f16 Ah[64 * 72];          // 9 KB
    __shared__ float bs[256];
    int tid = threadIdx.x;
    int row0 = blockIdx.x * 64;

    if (tid < 256) bs[tid] = bias[tid];

    // full W staging: 2048 octets, conflict-free
    for (int i = tid; i < 2048; i += 512) {
        int m = i & 15, q = (i >> 4) & 3, ks = (i >> 6) & 1, t = i >> 7;
        int col = 16 * t + m;
        int k0 = ks * 32 + q * 8;
        f16x8 v;
#pragma unroll
        for (int j = 0; j < 8; j++) v[j] = (f16)W[(k0 + j) * 256 + col];
        *(f16x8*)&WB[i * 8] = v;
    }

    int lane = tid & 63, wid = tid >> 6;  // wid 0..7
    int g = lane >> 4, fg = lane & 15;

    // gather phase: P(hd) rows -> Ah ; 32 node-slots per round, 2 rounds
    for (int r = 0; r < 2; r++) {
        int no = 32 * r + 4 * wid + g;
        int d = row0 + no;
        float vx = 0.f, vy = 0.f, vz = 0.f, vw = 0.f;
        if (d < n) {
            float dd = dinv[d];
            float ax, ay, az, aw;
            GCN_GATHER(hd, d, fg, ax, ay, az, aw, dd);
            vx = dd * ax; vy = dd * ay; vz = dd * az; vw = dd * aw;
        }
        half4 hv;
        hv.x = (f16)vx; hv.y = (f16)vy; hv.z = (f16)vz; hv.w = (f16)vw;
        *(half4*)&Ah[no * 72 + 4 * fg] = hv;
    }
    __syncthreads();

    int m = lane & 15, q = lane >> 4;
    int rowg = wid & 3, th = wid >> 2;

    f16x8 a0 = *(const f16x8*)&Ah[(16 * rowg + m) * 72 + 0 + 8 * q];
    f16x8 a1 = *(const f16x8*)&Ah[(16 * rowg + m) * 72 + 32 + 8 * q];

    int gr0 = row0 + 16 * rowg + 4 * q;
    bool full = (gr0 + 3 < n);
#pragma unroll 4
    for (int tl = 0; tl < 8; tl++) {
        int t = 8 * th + tl;
        f32x4 acc = (f32x4){0.f, 0.f, 0.f, 0.f};
        f16x8 b0 = *(const f16x8*)&WB[((t * 2 + 0) * 64 + lane) * 8];
        acc = __builtin_amdgcn_mfma_f32_16x16x32_f16(a0, b0, acc, 0, 0, 0);
        f16x8 b1 = *(const f16x8*)&WB[((t * 2 + 1) * 64 + lane) * 8];
        acc = __builtin_amdgcn_mfma_f32_16x16x32_f16(a1, b1, acc, 0, 0, 0);
        float bf = bs[16 * t + m];
        if (full) {
#pragma unroll
            for (int r = 0; r < 4; r++)
                out[(size_t)(gr0 + r) * 256 + 16 * t + m] = acc[r] + bf;
        } else {
#pragma unroll
            for (int r = 0; r < 4; r++)
                if (gr0 + r < n) out[(size_t)(gr0 + r) * 256 + 16 * t + m] = acc[r] + bf;
        }
    }
}

// ---------------- launch ----------------

extern "C" void kernel_launch(void* const* d_in, const int* in_sizes, int n_in,
                              void* d_out, int out_size, void* d_ws, size_t ws_size,
                              hipStream_t stream) {
    const float* x    = (const float*)d_in[0];
    const int*   ei   = (const int*)d_in[1];
    const float* Wenc = (const float*)d_in[3];
    const float* benc = (const float*)d_in[4];
    const float* Wz   = (const float*)d_in[5];
    const float* bz   = (const float*)d_in[6];
    const float* Wd   = (const float*)d_in[7];
    const float* bd   = (const float*)d_in[8];
    const float* Wdec = (const float*)d_in[9];
    const float* bdec = (const float*)d_in[10];
    const float* Wc   = (const float*)d_in[11];
    const float* bc   = (const float*)d_in[12];

    int n = in_sizes[0] / 256;
    int E = in_sizes[1] / 2;
    const int* src = ei;
    const int* dst = ei + E;

    int nbk = (n + BKT_SZ - 1) >> BKT_SH;
    int nbin = (E + EB - 1) / EB;

    char* w = (char*)d_ws;
    size_t off = 0;
    auto alloc = [&](size_t bytes) {
        void* p = w + off;
        off = (off + bytes + 255) & ~(size_t)255;
        return p;
    };
    int*      row_ptr = (int*)alloc(sizeof(int) * (n + 1));
    int*      ssorted = (int*)alloc(sizeof(int) * E);
    unsigned* ebuf    = (unsigned*)alloc(sizeof(unsigned) * (size_t)nbk * BCAP);
    float*    dinv    = (float*)alloc(sizeof(float) * n);
    int*      bcur    = (int*)alloc(sizeof(int) * 256);
    f16*      bufA    = (f16*)alloc(sizeof(f16) * (size_t)n * 64);  // h1pre
    f16*      bufB    = (f16*)alloc(sizeof(f16) * (size_t)n * 64);  // hd
    (void)ws_size; (void)n_in; (void)out_size;

    float* out_xr = (float*)d_out;
    float* out_z  = out_xr + (size_t)n * 256;
    float* out_p  = out_z + (size_t)n * 32;

    int tiles = (n + 63) / 64;
    int th = tiles / 2;

    hipMemsetAsync(bcur, 0, sizeof(int) * 256, stream);

    // phase 1: binning || gemm1 tiles [0, th)
    k_p1<<<dim3(nbin + th), dim3(256), 0, stream>>>(src, dst, E, bcur, ebuf,
                                                    x, Wenc, bufA, n, nbin, 0);
    // phase 2: per-bucket CSR || gemm1 tiles [th, tiles)
    k_p2<<<dim3(nbk + (tiles - th)), dim3(256), 0, stream>>>(ebuf, bcur, n, E, row_ptr, dinv, ssorted,
                                                             x, Wenc, bufA, nbk, th);

    // fused prop1 + middle: z (out), pred (out), hd -> bufB
    k_midf<<<dim3(tiles), dim3(512), 0, stream>>>(bufA, row_ptr, ssorted, dinv, benc,
                                                  Wz, bz, Wd, bd, Wc, bc,
                                                  bufB, out_z, out_p, n);

    // fused prop2 + decoder GEMM: x_recon = P(bufB) @ W_dec + b_dec
    k_decf<<<dim3(tiles), dim3(512), 0, stream>>>(bufB, row_ptr, ssorted, dinv,
                                                  Wdec, bdec, out_xr, n);
}